// Round 5
// baseline (234.933 us; speedup 1.0000x reference)
//
#include <hip/hip_runtime.h>

typedef short s16x8 __attribute__((ext_vector_type(8)));
typedef float fx4 __attribute__((ext_vector_type(4)));

#define NROWS 65536
#define BM 64
#define PSTR 133   // 133 mod 32 = 5 (odd, invertible) -> ~2-way worst LDS aliasing

#define MFMA(a, b, c) __builtin_amdgcn_mfma_f32_16x16x32_bf16((a), (b), (c), 0, 0, 0)

__device__ __forceinline__ unsigned short f2bf(float f) {
  union { float f; unsigned u; } v; v.f = f;
  unsigned r = v.u + 0x7fffu + ((v.u >> 16) & 1u);  // RNE
  return (unsigned short)(r >> 16);
}

// LDS-only barrier: does NOT drain vmcnt -> in-flight global loads (B prefetch)
// and fire-and-forget out[] stores survive. All cross-wave handoffs are LDS.
__device__ __forceinline__ void bar_lds() {
  asm volatile("s_waitcnt lgkmcnt(0)\n\ts_barrier" ::: "memory");
}

// ---------------------------------------------------------------------------
// Pack kernel.
//  blocks 0..1023   : W3P  idx=(((t*8+ks)*4+kc)*128+n)*8+e ; n<64 -> V col t*65+n,
//                     else W col 520+t*64+(n-64); value bf16(W3[k][c]), k=ks*32+kc*8+e
//  blocks 1024..1039: W3X  idx=((ks*4+kc)*16+n)*8+e ; n<8 -> V col n*65+64 else 0
//  blocks 1040..1047: W12 = W1@W2 (f32 acc -> bf16), B-frag order W12P[c*8+k]
//  block  1048      : b12 = b1@W2 + b2 (f32)
// ---------------------------------------------------------------------------
__global__ void pack_weights(const float* __restrict__ W1, const float* __restrict__ b1,
                             const float* __restrict__ W2, const float* __restrict__ b2,
                             const float* __restrict__ W3,
                             unsigned short* __restrict__ W12P, float* __restrict__ b12,
                             unsigned short* __restrict__ W3P, unsigned short* __restrict__ W3X) {
  int blk = blockIdx.x, tid = threadIdx.x;
  if (blk < 1024) {
    int i3 = blk * 256 + tid;
    int e = i3 & 7, n = (i3 >> 3) & 127, kc = (i3 >> 10) & 3, ks = (i3 >> 12) & 7, t = i3 >> 15;
    int k = ks * 32 + kc * 8 + e;
    int c = (n < 64) ? (t * 65 + n) : (520 + t * 64 + (n - 64));
    W3P[i3] = f2bf(W3[k * 1032 + c]);
  } else if (blk < 1040) {
    int ix = (blk - 1024) * 256 + tid;
    int e = ix & 7, n = (ix >> 3) & 15, kc = (ix >> 7) & 3, ks = ix >> 9;
    int k = ks * 32 + kc * 8 + e;
    float v = (n < 8) ? W3[k * 1032 + n * 65 + 64] : 0.0f;
    W3X[ix] = f2bf(v);
  } else if (blk < 1048) {
    int k = blk - 1040, c = tid;
    float s = 0.0f;
    for (int m = 0; m < 256; m++) s += W1[k * 256 + m] * W2[m * 256 + c];
    W12P[c * 8 + k] = f2bf(s);
  } else {
    int c = tid;
    float s = b2[c];
    for (int m = 0; m < 256; m++) s += b1[m] * W2[m * 256 + c];
    b12[c] = s;
  }
}

// ---------------------------------------------------------------------------
// Fused MLP + piecewise-quadratic transform. 256 threads (4 waves), 64 rows/block.
// Layer1+2 collapsed into one K=8 MFMA pass (W12 = W1@W2, f32-accumulated).
// GEMM3 2D-partitioned: wave w owns rows [32*(w>>1),+32) x cols [64*(w&1),+64)
// -> a3 only 64 regs (total live ~140 -> 3 waves/SIMD under (256,3)).
// Single params buffer + 2 LDS-only barriers per t -> LDS 41216 B -> 3 blocks/CU.
// LDS map:
//   P  [0,34048)       : params f32 [64][133]; h bf16 [64][256] swizzled aliases it
//   xt [34048,36096)   : [64][8] f32
//   v64[36096,38144)   : [64][8] f32 (raw 65th-V params)
//   lj [38144,40192)   : [64][8] f32
//   XC [40192,41216)   : xc bf16 [64][8] (prologue only)
// ---------------------------------------------------------------------------
__global__ __launch_bounds__(256, 3) void fused_pwquad(
    const float* __restrict__ x, const float* __restrict__ b3,
    const unsigned short* __restrict__ W12P, const float* __restrict__ b12,
    const unsigned short* __restrict__ W3P, const unsigned short* __restrict__ W3X,
    float* __restrict__ out)
{
  __shared__ char smem[41216];
  char*  H     = smem;                 // aliases P
  float* P     = (float*)smem;
  float* xt_s  = (float*)(smem + 34048);
  float* v64_s = (float*)(smem + 36096);
  float* lj_s  = (float*)(smem + 38144);
  char*  XC    = smem + 40192;

  const int tid  = threadIdx.x;
  const int lane = tid & 63;
  const int w    = tid >> 6;
  const int kc   = lane >> 4;
  const int l15  = lane & 15;
  const int rh   = w >> 1;   // row-half for GEMM3
  const int ch   = w & 1;    // col-half for GEMM3
  const int r0   = blockIdx.x * BM;

  // ---- phase 0: load x tile; emit copied (even) z cols; stash xc(bf16)/xt ----
  {
    const float4* xin = (const float4*)(x + (size_t)r0 * 16);
    float4 v = xin[tid];
    int row = tid >> 2, q = tid & 3;
    out[(size_t)(r0 + row) * 16 + 4 * q + 0] = fminf(v.x, 1.0f);
    out[(size_t)(r0 + row) * 16 + 4 * q + 2] = fminf(v.z, 1.0f);
    unsigned pk = (unsigned)f2bf(v.x) | ((unsigned)f2bf(v.z) << 16);
    *(unsigned*)(XC + row * 16 + q * 4) = pk;
    float2 t2; t2.x = v.y; t2.y = v.w;
    *(float2*)(xt_s + row * 8 + 2 * q) = t2;
  }
  bar_lds();

  // ---- GEMM-h: h = relu(xc @ W12 + b12), K=8 (one MFMA k-step) ----
  {
    s16x8 ah[4] = {};
    if (kc == 0) {
      #pragma unroll
      for (int m = 0; m < 4; m++) ah[m] = *(const s16x8*)(XC + (m * 16 + l15) * 16);
    }
    s16x8 bh[4];
    #pragma unroll
    for (int nt = 0; nt < 4; nt++)
      bh[nt] = *(const s16x8*)(W12P + (size_t)(w * 64 + nt * 16 + l15) * 8);
    fx4 acc[4][4];
    #pragma unroll
    for (int m = 0; m < 4; m++)
      #pragma unroll
      for (int nt = 0; nt < 4; nt++) acc[m][nt] = (fx4){0.f, 0.f, 0.f, 0.f};
    #pragma unroll
    for (int m = 0; m < 4; m++)
      #pragma unroll
      for (int nt = 0; nt < 4; nt++) acc[m][nt] = MFMA(ah[m], bh[nt], acc[m][nt]);
    #pragma unroll
    for (int nt = 0; nt < 4; nt++) {
      int col = w * 64 + nt * 16 + l15;
      float bias = b12[col];
      #pragma unroll
      for (int m = 0; m < 4; m++) {
        #pragma unroll
        for (int rg = 0; rg < 4; rg++) {
          int row = m * 16 + kc * 4 + rg;
          float v = fmaxf(acc[m][nt][rg] + bias, 0.0f);
          int byte = (row << 9) + (col << 1);
          byte ^= ((row & 7) << 4);
          *(unsigned short*)(H + byte) = f2bf(v);
        }
      }
    }
  }
  bar_lds();

  // ---- hoist A-frags for this wave's 32 GEMM3 rows; V65 GEMM (rows [16w,+16)) ----
  s16x8 a3[2][8];
  #pragma unroll
  for (int mi = 0; mi < 2; mi++) {
    #pragma unroll
    for (int ks = 0; ks < 8; ks++) {
      int row = rh * 32 + mi * 16 + l15;
      int byte = (row << 9) + ks * 64 + (kc << 4);
      byte ^= ((row & 7) << 4);
      a3[mi][ks] = *(const s16x8*)(H + byte);
    }
  }
  {
    // wave w's a3[w&1] holds global rows [16w, 16w+16)
    fx4 accx = (fx4){0.f, 0.f, 0.f, 0.f};
    #pragma unroll
    for (int ks = 0; ks < 8; ks++) {
      s16x8 bx = *(const s16x8*)(W3X + ((size_t)(ks * 4 + kc) * 16 + l15) * 8);
      accx = (ch == 0) ? MFMA(a3[0][ks], bx, accx) : MFMA(a3[1][ks], bx, accx);
    }
    if (l15 < 8) {
      float bias = b3[l15 * 65 + 64];
      #pragma unroll
      for (int rg = 0; rg < 4; rg++) {
        int row = w * 16 + kc * 4 + rg;
        v64_s[row * 8 + l15] = accx[rg] + bias;
      }
    }
  }
  bar_lds();  // H dead -> P usable; v64/xt visible

  // B-frag prefetch (t=0, ks=0): 4 col-tiles of this wave's col-half
  s16x8 bpre[4];
  #pragma unroll
  for (int nt = 0; nt < 4; nt++)
    bpre[nt] = *(const s16x8*)(W3P + ((size_t)kc * 128 + ch * 64 + nt * 16 + l15) * 8);

  #pragma unroll 1
  for (int t = 0; t < 8; t++) {
    fx4 acc3[2][4];
    #pragma unroll
    for (int mi = 0; mi < 2; mi++)
      #pragma unroll
      for (int nt = 0; nt < 4; nt++) acc3[mi][nt] = (fx4){0.f, 0.f, 0.f, 0.f};

    #pragma unroll
    for (int mi = 0; mi < 2; mi++)
      #pragma unroll
      for (int nt = 0; nt < 4; nt++) acc3[mi][nt] = MFMA(a3[mi][0], bpre[nt], acc3[mi][nt]);

    #pragma unroll
    for (int ks = 1; ks < 8; ks++) {
      s16x8 b[4];
      #pragma unroll
      for (int nt = 0; nt < 4; nt++)
        b[nt] = *(const s16x8*)(W3P + ((size_t)((t * 8 + ks) * 4 + kc) * 128 + ch * 64 + nt * 16 + l15) * 8);
      #pragma unroll
      for (int mi = 0; mi < 2; mi++)
        #pragma unroll
        for (int nt = 0; nt < 4; nt++) acc3[mi][nt] = MFMA(a3[mi][ks], b[nt], acc3[mi][nt]);
    }

    if (t < 7) {  // prefetch next t's ks0 frags; survive the LDS-only barriers
      #pragma unroll
      for (int nt = 0; nt < 4; nt++)
        bpre[nt] = *(const s16x8*)(W3P + ((size_t)((t + 1) * 32 + kc) * 128 + ch * 64 + nt * 16 + l15) * 8);
    }

    bar_lds();  // A: postprocess(t-1) finished reading P

    // epilogue: wave w writes rows [32rh,+32) x cols [64ch,+64)
    #pragma unroll
    for (int nt = 0; nt < 4; nt++) {
      int nn = nt * 16 + l15;                       // 0..63 within the half
      float bias = ch ? b3[520 + t * 64 + nn] : b3[t * 65 + nn];
      int ci = ch ? (65 + nn) : nn;                 // hole at 64 (V65 in v64_s)
      #pragma unroll
      for (int mi = 0; mi < 2; mi++) {
        #pragma unroll
        for (int rg = 0; rg < 4; rg++) {
          int row = rh * 32 + mi * 16 + kc * 4 + rg;
          P[row * PSTR + ci] = acc3[mi][nt][rg] + bias;
        }
      }
    }

    bar_lds();  // B: params complete

    // ---------- postprocess channel t: 4 lanes per row, raw-sum algebra ----------
    {
      int row = tid >> 2, sub = tid & 3;
      const float* prow = P + row * PSTR;
      float xtv = xt_s[row * 8 + t];

      // W softmax (unnormalized: invS factored out; cancels in C)
      float wj[16];
      #pragma unroll
      for (int i = 0; i < 4; i++) {
        float4 v4 = *(const float4*)(prow + 65 + sub * 16 + 4 * i);
        wj[4*i] = v4.x; wj[4*i+1] = v4.y; wj[4*i+2] = v4.z; wj[4*i+3] = v4.w;
      }
      float wmax = wj[0];
      #pragma unroll
      for (int j = 1; j < 16; j++) wmax = fmaxf(wmax, wj[j]);
      wmax = fmaxf(wmax, __shfl_xor(wmax, 1, 64));
      wmax = fmaxf(wmax, __shfl_xor(wmax, 2, 64));

      float esum = 0.0f;
      #pragma unroll
      for (int j = 0; j < 16; j++) { wj[j] = __expf(wj[j] - wmax); esum += wj[j]; }

      int gbase = lane & ~3;
      float g0 = __shfl(esum, gbase + 0, 64);
      float g1 = __shfl(esum, gbase + 1, 64);
      float g2 = __shfl(esum, gbase + 2, 64);
      float g3 = __shfl(esum, gbase + 3, 64);
      float S = (g0 + g1) + (g2 + g3);
      float ebase = 0.0f;
      if (sub > 0) ebase += g0;
      if (sub > 1) ebase += g1;
      if (sub > 2) ebase += g2;
      float xs = xtv * S;   // compare raw cumsum against xt*S

      // V params, vectorized load
      float vv[17];
      #pragma unroll
      for (int i = 0; i < 4; i++) {
        float4 v4 = *(const float4*)(prow + sub * 16 + 4 * i);
        vv[4*i] = v4.x; vv[4*i+1] = v4.y; vv[4*i+2] = v4.z; vv[4*i+3] = v4.w;
      }
      vv[16] = (sub == 3) ? v64_s[row * 8 + t] : prow[sub * 16 + 16];

      // fused stream: ev, dl, prefix(cpart), crossing capture — all RAW (no invS)
      float run = ebase;
      float evc = __expf(vv[0]);
      float evprev = evc, tlast = 0.0f;
      float dl = 0.0f, cpart = 0.0f;
      float wpadc = 0.0f, wbbc = 1.0f, evb = evc, evb1 = evc;
      int cnt = 0;
      #pragma unroll
      for (int j = 0; j < 16; j++) {
        float evn = __expf(vv[j + 1]);
        float wbj = wj[j];
        float nw = run + wbj;
        float term = (evc + evn) * wbj;
        bool le = (nw <= xs);
        bool hit = (!le) && (run <= xs);
        dl += term;
        if (le) { cpart += term; cnt++; }
        if (hit) { wpadc = run; wbbc = wbj; evb = evc; evb1 = evn; }
        tlast = term;
        evprev = evc;
        run = nw; evc = evn;
      }
      int bloc = (cnt < 16) ? (sub * 16 + cnt) : 64;
      int bmin = min(bloc, __shfl_xor(bloc, 1, 64));
      bmin = min(bmin, __shfl_xor(bmin, 2, 64));

      float d0 = __shfl(dl, gbase + 0, 64);
      float d1 = __shfl(dl, gbase + 1, 64);
      float d2 = __shfl(dl, gbase + 2, 64);
      float d3 = __shfl(dl, gbase + 3, 64);
      float dltot = (d0 + d1) + (d2 + d3);
      float cbase2 = 0.0f;
      if (sub > 0) cbase2 += d0;
      if (sub > 1) cbase2 += d1;
      if (sub > 2) cbase2 += d2;

      if (bmin == 64) {  // no strict crossing: continuous fallback b=63 (sub3 owns)
        wbbc = wj[15];
        wpadc = run - wbbc;
        evb = evprev; evb1 = evc;
        cpart = dl - tlast;
        bmin = 63;
      }

      if (sub == (bmin >> 4)) {
        float alpha = (xs - wpadc) / wbbc;          // invS cancels
        float Cnum = (alpha * (evb + 0.5f * alpha * (evb1 - evb))) * wbbc
                   + 0.5f * (cbase2 + cpart);
        out[(size_t)(r0 + row) * 16 + 2 * t + 1] = fminf(Cnum / (0.5f * dltot), 1.0f);
        float qn = evb + alpha * (evb1 - evb);
        float denomt = 0.5f * dltot / S;            // true denom
        lj_s[row * 8 + t] = __logf(qn) - __logf(denomt);
      }
    }
    // next epilogue is fenced by barA(t+1)
  }

  // ---- log_J = sum_t log(q_t): wave w emits its own 16 rows (intra-wave lj) ----
  if (lane < 16) {
    int row = w * 16 + lane;
    float s = 0.0f;
    #pragma unroll
    for (int t = 0; t < 8; t++) s += lj_s[row * 8 + t];
    out[(size_t)NROWS * 16 + r0 + row] = s;
  }
}

extern "C" void kernel_launch(void* const* d_in, const int* in_sizes, int n_in,
                              void* d_out, int out_size, void* d_ws, size_t ws_size,
                              hipStream_t stream) {
  const float* x  = (const float*)d_in[0];
  const float* W1 = (const float*)d_in[1];
  const float* b1 = (const float*)d_in[2];
  const float* W2 = (const float*)d_in[3];
  const float* b2 = (const float*)d_in[4];
  const float* W3 = (const float*)d_in[5];
  const float* b3 = (const float*)d_in[6];

  unsigned short* W12P = (unsigned short*)d_ws;                      // 4096 B
  float*          b12  = (float*)((char*)d_ws + 4096);               // 1024 B
  unsigned short* W3P  = (unsigned short*)((char*)d_ws + 5120);      // 524288 B
  unsigned short* W3X  = (unsigned short*)((char*)d_ws + 529408);    // 8192 B

  pack_weights<<<dim3(1049), dim3(256), 0, stream>>>(W1, b1, W2, b2, W3, W12P, b12, W3P, W3X);
  fused_pwquad<<<dim3(NROWS / BM), dim3(256), 0, stream>>>(
      x, b3, W12P, b12, W3P, W3X, (float*)d_out);
}

// Round 6
// 213.734 us; speedup vs baseline: 1.0992x; 1.0992x over previous
//
#include <hip/hip_runtime.h>

typedef short s16x8 __attribute__((ext_vector_type(8)));
typedef float fx4 __attribute__((ext_vector_type(4)));

#define NROWS 65536
#define BM 64
#define PSTR 133   // 133 mod 32 = 5 (odd, invertible) -> conflict-free patterns below

#define MFMA(a, b, c) __builtin_amdgcn_mfma_f32_16x16x32_bf16((a), (b), (c), 0, 0, 0)

__device__ __forceinline__ unsigned short f2bf(float f) {
  union { float f; unsigned u; } v; v.f = f;
  unsigned r = v.u + 0x7fffu + ((v.u >> 16) & 1u);  // RNE
  return (unsigned short)(r >> 16);
}

// LDS-only barrier: does NOT drain vmcnt -> in-flight global loads (B prefetch)
// and fire-and-forget out[] stores survive. All cross-wave handoffs are LDS.
__device__ __forceinline__ void bar_lds() {
  asm volatile("s_waitcnt lgkmcnt(0)\n\ts_barrier" ::: "memory");
}

// ---------------------------------------------------------------------------
// Pack kernel.
//  blocks 0..1023   : W3P  idx=(((t*8+ks)*4+kc)*128+n)*8+e ; n<64 -> V col t*65+n,
//                     else W col 520+t*64+(n-64); value bf16(W3[k][c]), k=ks*32+kc*8+e
//  blocks 1024..1039: W3X  idx=((ks*4+kc)*16+n)*8+e ; n<8 -> V col n*65+64 else 0
//  blocks 1040..1047: W12 = W1@W2 (f32 acc -> bf16), B-frag order W12P[c*8+k]
//  block  1048      : b12 = b1@W2 + b2 (f32)
// ---------------------------------------------------------------------------
__global__ void pack_weights(const float* __restrict__ W1, const float* __restrict__ b1,
                             const float* __restrict__ W2, const float* __restrict__ b2,
                             const float* __restrict__ W3,
                             unsigned short* __restrict__ W12P, float* __restrict__ b12,
                             unsigned short* __restrict__ W3P, unsigned short* __restrict__ W3X) {
  int blk = blockIdx.x, tid = threadIdx.x;
  if (blk < 1024) {
    int i3 = blk * 256 + tid;
    int e = i3 & 7, n = (i3 >> 3) & 127, kc = (i3 >> 10) & 3, ks = (i3 >> 12) & 7, t = i3 >> 15;
    int k = ks * 32 + kc * 8 + e;
    int c = (n < 64) ? (t * 65 + n) : (520 + t * 64 + (n - 64));
    W3P[i3] = f2bf(W3[k * 1032 + c]);
  } else if (blk < 1040) {
    int ix = (blk - 1024) * 256 + tid;
    int e = ix & 7, n = (ix >> 3) & 15, kc = (ix >> 7) & 3, ks = ix >> 9;
    int k = ks * 32 + kc * 8 + e;
    float v = (n < 8) ? W3[k * 1032 + n * 65 + 64] : 0.0f;
    W3X[ix] = f2bf(v);
  } else if (blk < 1048) {
    int k = blk - 1040, c = tid;
    float s = 0.0f;
    for (int m = 0; m < 256; m++) s += W1[k * 256 + m] * W2[m * 256 + c];
    W12P[c * 8 + k] = f2bf(s);
  } else {
    int c = tid;
    float s = b2[c];
    for (int m = 0; m < 256; m++) s += b1[m] * W2[m * 256 + c];
    b12[c] = s;
  }
}

// ---------------------------------------------------------------------------
// Fused MLP + piecewise-quadratic transform. 256 threads (4 waves), 64 rows/block.
// Layer1+2 collapsed into one K=8 MFMA pass (W12 = W1@W2, f32-accumulated).
// GEMM3 2D-partitioned: wave w owns rows [32*(w>>1),+32) x cols [64*(w&1),+64)
// -> a3 = 64 regs. B-frags: WAR-bounded 2-deep pipeline (bA/bB, max 32 live regs
// by construction -- the reload of each buffer sits AFTER its MFMAs, so the
// compiler CANNOT hoist loads; R5's full unroll hoisted 112 regs -> spill).
// Postprocess streams V from LDS (no vv[17] array).
// Single params buffer + 2 LDS-only barriers per t -> LDS 41216 B -> 3 blocks/CU.
// LDS map:
//   P  [0,34048)       : params f32 [64][133]; h bf16 [64][256] swizzled aliases it
//   xt [34048,36096)   : [64][8] f32
//   v64[36096,38144)   : [64][8] f32 (raw 65th-V params)
//   lj [38144,40192)   : [64][8] f32
//   XC [40192,41216)   : xc bf16 [64][8] (prologue only)
// ---------------------------------------------------------------------------
__global__ __launch_bounds__(256, 3) void fused_pwquad(
    const float* __restrict__ x, const float* __restrict__ b3,
    const unsigned short* __restrict__ W12P, const float* __restrict__ b12,
    const unsigned short* __restrict__ W3P, const unsigned short* __restrict__ W3X,
    float* __restrict__ out)
{
  __shared__ char smem[41216];
  char*  H     = smem;                 // aliases P
  float* P     = (float*)smem;
  float* xt_s  = (float*)(smem + 34048);
  float* v64_s = (float*)(smem + 36096);
  float* lj_s  = (float*)(smem + 38144);
  char*  XC    = smem + 40192;

  const int tid  = threadIdx.x;
  const int lane = tid & 63;
  const int w    = tid >> 6;
  const int kc   = lane >> 4;
  const int l15  = lane & 15;
  const int rh   = w >> 1;   // row-half for GEMM3
  const int ch   = w & 1;    // col-half for GEMM3
  const int r0   = blockIdx.x * BM;

  // ---- phase 0: load x tile; emit copied (even) z cols; stash xc(bf16)/xt ----
  {
    const float4* xin = (const float4*)(x + (size_t)r0 * 16);
    float4 v = xin[tid];
    int row = tid >> 2, q = tid & 3;
    out[(size_t)(r0 + row) * 16 + 4 * q + 0] = fminf(v.x, 1.0f);
    out[(size_t)(r0 + row) * 16 + 4 * q + 2] = fminf(v.z, 1.0f);
    unsigned pk = (unsigned)f2bf(v.x) | ((unsigned)f2bf(v.z) << 16);
    *(unsigned*)(XC + row * 16 + q * 4) = pk;
    float2 t2; t2.x = v.y; t2.y = v.w;
    *(float2*)(xt_s + row * 8 + 2 * q) = t2;
  }
  bar_lds();

  // ---- GEMM-h: h = relu(xc @ W12 + b12), K=8 (one MFMA k-step) ----
  {
    s16x8 ah[4] = {};
    if (kc == 0) {
      #pragma unroll
      for (int m = 0; m < 4; m++) ah[m] = *(const s16x8*)(XC + (m * 16 + l15) * 16);
    }
    s16x8 bh[4];
    #pragma unroll
    for (int nt = 0; nt < 4; nt++)
      bh[nt] = *(const s16x8*)(W12P + (size_t)(w * 64 + nt * 16 + l15) * 8);
    fx4 acc[4][4];
    #pragma unroll
    for (int m = 0; m < 4; m++)
      #pragma unroll
      for (int nt = 0; nt < 4; nt++) acc[m][nt] = (fx4){0.f, 0.f, 0.f, 0.f};
    #pragma unroll
    for (int m = 0; m < 4; m++)
      #pragma unroll
      for (int nt = 0; nt < 4; nt++) acc[m][nt] = MFMA(ah[m], bh[nt], acc[m][nt]);
    #pragma unroll
    for (int nt = 0; nt < 4; nt++) {
      int col = w * 64 + nt * 16 + l15;
      float bias = b12[col];
      #pragma unroll
      for (int m = 0; m < 4; m++) {
        #pragma unroll
        for (int rg = 0; rg < 4; rg++) {
          int row = m * 16 + kc * 4 + rg;
          float v = fmaxf(acc[m][nt][rg] + bias, 0.0f);
          int byte = (row << 9) + (col << 1);
          byte ^= ((row & 7) << 4);
          *(unsigned short*)(H + byte) = f2bf(v);
        }
      }
    }
  }
  bar_lds();

  // ---- hoist A-frags for this wave's 32 GEMM3 rows; V65 GEMM (rows [16w,+16)) ----
  s16x8 a3[2][8];
  #pragma unroll
  for (int mi = 0; mi < 2; mi++) {
    #pragma unroll
    for (int ks = 0; ks < 8; ks++) {
      int row = rh * 32 + mi * 16 + l15;
      int byte = (row << 9) + ks * 64 + (kc << 4);
      byte ^= ((row & 7) << 4);
      a3[mi][ks] = *(const s16x8*)(H + byte);
    }
  }
  {
    // wave w's a3[ch] holds global rows [16w, 16w+16)
    fx4 accx = (fx4){0.f, 0.f, 0.f, 0.f};
    #pragma unroll
    for (int ks = 0; ks < 8; ks++) {
      s16x8 bx = *(const s16x8*)(W3X + ((size_t)(ks * 4 + kc) * 16 + l15) * 8);
      accx = (ch == 0) ? MFMA(a3[0][ks], bx, accx) : MFMA(a3[1][ks], bx, accx);
    }
    if (l15 < 8) {
      float bias = b3[l15 * 65 + 64];
      #pragma unroll
      for (int rg = 0; rg < 4; rg++) {
        int row = w * 16 + kc * 4 + rg;
        v64_s[row * 8 + l15] = accx[rg] + bias;
      }
    }
  }
  bar_lds();  // H dead -> P usable; v64/xt visible

  // B-frag base for this wave's col-half; element offset helper
  #define BOFF(tt, ks, nt) (((size_t)(((tt) * 8 + (ks)) * 4 + kc) * 128 + ch * 64 + (nt) * 16 + l15) * 8)

  // pipeline prologue: bA <- (t=0, ks=0)
  s16x8 bA[4], bB[4];
  #pragma unroll
  for (int nt = 0; nt < 4; nt++) bA[nt] = *(const s16x8*)(W3P + BOFF(0, 0, nt));

  #pragma unroll 1
  for (int t = 0; t < 8; t++) {
    fx4 acc3[2][4];
    #pragma unroll
    for (int mi = 0; mi < 2; mi++)
      #pragma unroll
      for (int nt = 0; nt < 4; nt++) acc3[mi][nt] = (fx4){0.f, 0.f, 0.f, 0.f};

    // 2-deep WAR-bounded pipeline over ks: bA/bB alternate. Reload of a buffer
    // is placed AFTER the MFMAs reading it -> compiler cannot hoist (max 32 live).
    #pragma unroll
    for (int kp = 0; kp < 4; kp++) {
      const int ks0 = 2 * kp, ks1 = 2 * kp + 1;
      #pragma unroll
      for (int nt = 0; nt < 4; nt++) bB[nt] = *(const s16x8*)(W3P + BOFF(t, ks1, nt));
      #pragma unroll
      for (int mi = 0; mi < 2; mi++)
        #pragma unroll
        for (int nt = 0; nt < 4; nt++) acc3[mi][nt] = MFMA(a3[mi][ks0], bA[nt], acc3[mi][nt]);
      if (kp < 3) {
        #pragma unroll
        for (int nt = 0; nt < 4; nt++) bA[nt] = *(const s16x8*)(W3P + BOFF(t, ks0 + 2, nt));
      } else if (t < 7) {  // fold next-t ks0 prefetch into the last slot
        #pragma unroll
        for (int nt = 0; nt < 4; nt++) bA[nt] = *(const s16x8*)(W3P + BOFF(t + 1, 0, nt));
      }
      #pragma unroll
      for (int mi = 0; mi < 2; mi++)
        #pragma unroll
        for (int nt = 0; nt < 4; nt++) acc3[mi][nt] = MFMA(a3[mi][ks1], bB[nt], acc3[mi][nt]);
    }

    bar_lds();  // A: postprocess(t-1) finished reading P

    // epilogue: wave w writes rows [32rh,+32) x cols [64ch,+64)
    #pragma unroll
    for (int nt = 0; nt < 4; nt++) {
      int nn = nt * 16 + l15;                       // 0..63 within the half
      float bias = ch ? b3[520 + t * 64 + nn] : b3[t * 65 + nn];
      int ci = ch ? (65 + nn) : nn;                 // hole at 64 (V65 in v64_s)
      #pragma unroll
      for (int mi = 0; mi < 2; mi++) {
        #pragma unroll
        for (int rg = 0; rg < 4; rg++) {
          int row = rh * 32 + mi * 16 + kc * 4 + rg;
          P[row * PSTR + ci] = acc3[mi][nt][rg] + bias;
        }
      }
    }

    bar_lds();  // B: params complete

    // ---------- postprocess channel t: 4 lanes/row, raw-sum algebra, LDS-streamed V ----------
    {
      int row = tid >> 2, sub = tid & 3;
      const float* prow = P + row * PSTR;
      float xtv = xt_s[row * 8 + t];

      // W softmax (unnormalized: invS factored out; cancels in C)
      float wj[16];
      #pragma unroll
      for (int i = 0; i < 4; i++) {
        float4 v4 = *(const float4*)(prow + 65 + sub * 16 + 4 * i);
        wj[4*i] = v4.x; wj[4*i+1] = v4.y; wj[4*i+2] = v4.z; wj[4*i+3] = v4.w;
      }
      float wmax = wj[0];
      #pragma unroll
      for (int j = 1; j < 16; j++) wmax = fmaxf(wmax, wj[j]);
      wmax = fmaxf(wmax, __shfl_xor(wmax, 1, 64));
      wmax = fmaxf(wmax, __shfl_xor(wmax, 2, 64));

      float esum = 0.0f;
      #pragma unroll
      for (int j = 0; j < 16; j++) { wj[j] = __expf(wj[j] - wmax); esum += wj[j]; }

      int gbase = lane & ~3;
      float g0 = __shfl(esum, gbase + 0, 64);
      float g1 = __shfl(esum, gbase + 1, 64);
      float g2 = __shfl(esum, gbase + 2, 64);
      float g3 = __shfl(esum, gbase + 3, 64);
      float S = (g0 + g1) + (g2 + g3);
      float ebase = 0.0f;
      if (sub > 0) ebase += g0;
      if (sub > 1) ebase += g1;
      if (sub > 2) ebase += g2;
      float xs = xtv * S;   // compare raw cumsum against xt*S

      // fused stream: ev (from LDS, no array), dl, prefix(cpart), crossing capture
      float run = ebase;
      float evc = __expf(prow[sub * 16]);
      float evprev = evc, tlast = 0.0f;
      float dl = 0.0f, cpart = 0.0f;
      float wpadc = 0.0f, wbbc = 1.0f, evb = evc, evb1 = evc;
      int cnt = 0;
      #pragma unroll
      for (int j = 0; j < 16; j++) {
        float vr = (sub == 3 && j == 15) ? v64_s[row * 8 + t] : prow[sub * 16 + j + 1];
        float evn = __expf(vr);
        float wbj = wj[j];
        float nw = run + wbj;
        float term = (evc + evn) * wbj;
        bool le = (nw <= xs);
        bool hit = (!le) && (run <= xs);
        dl += term;
        if (le) { cpart += term; cnt++; }
        if (hit) { wpadc = run; wbbc = wbj; evb = evc; evb1 = evn; }
        tlast = term;
        evprev = evc;
        run = nw; evc = evn;
      }
      int bloc = (cnt < 16) ? (sub * 16 + cnt) : 64;
      int bmin = min(bloc, __shfl_xor(bloc, 1, 64));
      bmin = min(bmin, __shfl_xor(bmin, 2, 64));

      float d0 = __shfl(dl, gbase + 0, 64);
      float d1 = __shfl(dl, gbase + 1, 64);
      float d2 = __shfl(dl, gbase + 2, 64);
      float d3 = __shfl(dl, gbase + 3, 64);
      float dltot = (d0 + d1) + (d2 + d3);
      float cbase2 = 0.0f;
      if (sub > 0) cbase2 += d0;
      if (sub > 1) cbase2 += d1;
      if (sub > 2) cbase2 += d2;

      if (bmin == 64) {  // no strict crossing: continuous fallback b=63 (sub3 owns)
        wbbc = wj[15];
        wpadc = run - wbbc;
        evb = evprev; evb1 = evc;
        cpart = dl - tlast;
        bmin = 63;
      }

      if (sub == (bmin >> 4)) {
        float alpha = (xs - wpadc) / wbbc;          // invS cancels
        float Cnum = (alpha * (evb + 0.5f * alpha * (evb1 - evb))) * wbbc
                   + 0.5f * (cbase2 + cpart);
        out[(size_t)(r0 + row) * 16 + 2 * t + 1] = fminf(Cnum / (0.5f * dltot), 1.0f);
        float qn = evb + alpha * (evb1 - evb);
        float denomt = 0.5f * dltot / S;            // true denom
        lj_s[row * 8 + t] = __logf(qn) - __logf(denomt);
      }
    }
    // next epilogue is fenced by barA(t+1)
  }

  // ---- log_J = sum_t log(q_t): wave w emits its own 16 rows (intra-wave lj) ----
  if (lane < 16) {
    int row = w * 16 + lane;
    float s = 0.0f;
    #pragma unroll
    for (int t = 0; t < 8; t++) s += lj_s[row * 8 + t];
    out[(size_t)NROWS * 16 + r0 + row] = s;
  }
  #undef BOFF
}

extern "C" void kernel_launch(void* const* d_in, const int* in_sizes, int n_in,
                              void* d_out, int out_size, void* d_ws, size_t ws_size,
                              hipStream_t stream) {
  const float* x  = (const float*)d_in[0];
  const float* W1 = (const float*)d_in[1];
  const float* b1 = (const float*)d_in[2];
  const float* W2 = (const float*)d_in[3];
  const float* b2 = (const float*)d_in[4];
  const float* W3 = (const float*)d_in[5];
  const float* b3 = (const float*)d_in[6];

  unsigned short* W12P = (unsigned short*)d_ws;                      // 4096 B
  float*          b12  = (float*)((char*)d_ws + 4096);               // 1024 B
  unsigned short* W3P  = (unsigned short*)((char*)d_ws + 5120);      // 524288 B
  unsigned short* W3X  = (unsigned short*)((char*)d_ws + 529408);    // 8192 B

  pack_weights<<<dim3(1049), dim3(256), 0, stream>>>(W1, b1, W2, b2, W3, W12P, b12, W3P, W3X);
  fused_pwquad<<<dim3(NROWS / BM), dim3(256), 0, stream>>>(
      x, b3, W12P, b12, W3P, W3X, (float*)d_out);
}

// Round 7
// 98.033 us; speedup vs baseline: 2.3965x; 2.1802x over previous
//
#include <hip/hip_runtime.h>

typedef short s16x8 __attribute__((ext_vector_type(8)));
typedef float fx4 __attribute__((ext_vector_type(4)));

#define NROWS 65536
#define BM 64
#define PSTR 133   // 133 mod 32 = 5 (odd, invertible) -> benign LDS patterns

#define MFMA(a, b, c) __builtin_amdgcn_mfma_f32_16x16x32_bf16((a), (b), (c), 0, 0, 0)

__device__ __forceinline__ unsigned short f2bf(float f) {
  union { float f; unsigned u; } v; v.f = f;
  unsigned r = v.u + 0x7fffu + ((v.u >> 16) & 1u);  // RNE
  return (unsigned short)(r >> 16);
}

// LDS-only barrier: does NOT drain vmcnt -> in-flight global loads (B prefetch)
// and fire-and-forget out[] stores survive. All cross-wave handoffs are LDS.
__device__ __forceinline__ void bar_lds() {
  asm volatile("s_waitcnt lgkmcnt(0)\n\ts_barrier" ::: "memory");
}

// ---------------------------------------------------------------------------
// Pack kernel.
//  blocks 0..1023   : W3P  idx=(((t*8+ks)*4+kc)*128+n)*8+e ; n<64 -> V col t*65+n,
//                     else W col 520+t*64+(n-64); value bf16(W3[k][c]), k=ks*32+kc*8+e
//  blocks 1024..1039: W3X  idx=((ks*4+kc)*16+n)*8+e ; n<8 -> V col n*65+64 else 0
//  blocks 1040..1047: W12 = W1@W2 (f32 acc -> bf16), B-frag order W12P[c*8+k]
//  block  1048      : b12 = b1@W2 + b2 (f32)
// ---------------------------------------------------------------------------
__global__ void pack_weights(const float* __restrict__ W1, const float* __restrict__ b1,
                             const float* __restrict__ W2, const float* __restrict__ b2,
                             const float* __restrict__ W3,
                             unsigned short* __restrict__ W12P, float* __restrict__ b12,
                             unsigned short* __restrict__ W3P, unsigned short* __restrict__ W3X) {
  int blk = blockIdx.x, tid = threadIdx.x;
  if (blk < 1024) {
    int i3 = blk * 256 + tid;
    int e = i3 & 7, n = (i3 >> 3) & 127, kc = (i3 >> 10) & 3, ks = (i3 >> 12) & 7, t = i3 >> 15;
    int k = ks * 32 + kc * 8 + e;
    int c = (n < 64) ? (t * 65 + n) : (520 + t * 64 + (n - 64));
    W3P[i3] = f2bf(W3[k * 1032 + c]);
  } else if (blk < 1040) {
    int ix = (blk - 1024) * 256 + tid;
    int e = ix & 7, n = (ix >> 3) & 15, kc = (ix >> 7) & 3, ks = ix >> 9;
    int k = ks * 32 + kc * 8 + e;
    float v = (n < 8) ? W3[k * 1032 + n * 65 + 64] : 0.0f;
    W3X[ix] = f2bf(v);
  } else if (blk < 1048) {
    int k = blk - 1040, c = tid;
    float s = 0.0f;
    for (int m = 0; m < 256; m++) s += W1[k * 256 + m] * W2[m * 256 + c];
    W12P[c * 8 + k] = f2bf(s);
  } else {
    int c = tid;
    float s = b2[c];
    for (int m = 0; m < 256; m++) s += b1[m] * W2[m * 256 + c];
    b12[c] = s;
  }
}

// ---------------------------------------------------------------------------
// Fused MLP + piecewise-quadratic transform. 256 threads (4 waves), 64 rows/block.
// Layer1+2 collapsed into one K=8 MFMA pass (W12 = W1@W2, f32-accumulated).
// GEMM3 2D-partitioned: wave w owns rows [32*(w>>1),+32) x cols [64*(w&1),+64).
// Register plan for (256,3) (~168 combined budget):
//   acc: a3[2][8]=64 + acc3[2][4]=32.  arch: bA/bB 32 (WAR-bounded), ~16 misc.
//   NO wj[] array (scan recomputes exp from LDS); linearized B addressing.
// Single params buffer + 2 LDS-only barriers per t -> LDS 41216 B -> 3 blocks/CU.
// LDS map:
//   P  [0,34048)       : params f32 [64][133]; h bf16 [64][256] swizzled aliases it
//   xt [34048,36096)   : [64][8] f32
//   v64[36096,38144)   : [64][8] f32 (raw 65th-V params)
//   lj [38144,40192)   : [64][8] f32
//   XC [40192,41216)   : xc bf16 [64][8] (prologue only)
// ---------------------------------------------------------------------------
__global__ __launch_bounds__(256, 3) void fused_pwquad(
    const float* __restrict__ x, const float* __restrict__ b3,
    const unsigned short* __restrict__ W12P, const float* __restrict__ b12,
    const unsigned short* __restrict__ W3P, const unsigned short* __restrict__ W3X,
    float* __restrict__ out)
{
  __shared__ char smem[41216];
  char*  H     = smem;                 // aliases P
  float* P     = (float*)smem;
  float* xt_s  = (float*)(smem + 34048);
  float* v64_s = (float*)(smem + 36096);
  float* lj_s  = (float*)(smem + 38144);
  char*  XC    = smem + 40192;

  const int tid  = threadIdx.x;
  const int lane = tid & 63;
  const int w    = tid >> 6;
  const int kc   = lane >> 4;
  const int l15  = lane & 15;
  const int rh   = w >> 1;   // row-half for GEMM3
  const int ch   = w & 1;    // col-half for GEMM3
  const int r0   = blockIdx.x * BM;

  // ---- phase 0: load x tile; emit copied (even) z cols; stash xc(bf16)/xt ----
  {
    const float4* xin = (const float4*)(x + (size_t)r0 * 16);
    float4 v = xin[tid];
    int row = tid >> 2, q = tid & 3;
    out[(size_t)(r0 + row) * 16 + 4 * q + 0] = fminf(v.x, 1.0f);
    out[(size_t)(r0 + row) * 16 + 4 * q + 2] = fminf(v.z, 1.0f);
    unsigned pk = (unsigned)f2bf(v.x) | ((unsigned)f2bf(v.z) << 16);
    *(unsigned*)(XC + row * 16 + q * 4) = pk;
    float2 t2; t2.x = v.y; t2.y = v.w;
    *(float2*)(xt_s + row * 8 + 2 * q) = t2;
  }
  bar_lds();

  // ---- GEMM-h: h = relu(xc @ W12 + b12), K=8 (one MFMA k-step) ----
  {
    s16x8 ah[4] = {};
    if (kc == 0) {
      #pragma unroll
      for (int m = 0; m < 4; m++) ah[m] = *(const s16x8*)(XC + (m * 16 + l15) * 16);
    }
    s16x8 bh[4];
    #pragma unroll
    for (int nt = 0; nt < 4; nt++)
      bh[nt] = *(const s16x8*)(W12P + (size_t)(w * 64 + nt * 16 + l15) * 8);
    fx4 acc[4][4];
    #pragma unroll
    for (int m = 0; m < 4; m++)
      #pragma unroll
      for (int nt = 0; nt < 4; nt++) acc[m][nt] = (fx4){0.f, 0.f, 0.f, 0.f};
    #pragma unroll
    for (int m = 0; m < 4; m++)
      #pragma unroll
      for (int nt = 0; nt < 4; nt++) acc[m][nt] = MFMA(ah[m], bh[nt], acc[m][nt]);
    #pragma unroll
    for (int nt = 0; nt < 4; nt++) {
      int col = w * 64 + nt * 16 + l15;
      float bias = b12[col];
      #pragma unroll
      for (int m = 0; m < 4; m++) {
        #pragma unroll
        for (int rg = 0; rg < 4; rg++) {
          int row = m * 16 + kc * 4 + rg;
          float v = fmaxf(acc[m][nt][rg] + bias, 0.0f);
          int byte = (row << 9) + (col << 1);
          byte ^= ((row & 7) << 4);
          *(unsigned short*)(H + byte) = f2bf(v);
        }
      }
    }
  }
  bar_lds();

  // ---- hoist A-frags for this wave's 32 GEMM3 rows; V65 GEMM (rows [16w,+16)) ----
  s16x8 a3[2][8];
  #pragma unroll
  for (int mi = 0; mi < 2; mi++) {
    #pragma unroll
    for (int ks = 0; ks < 8; ks++) {
      int row = rh * 32 + mi * 16 + l15;
      int byte = (row << 9) + ks * 64 + (kc << 4);
      byte ^= ((row & 7) << 4);
      a3[mi][ks] = *(const s16x8*)(H + byte);
    }
  }
  {
    // wave w's a3[ch] holds global rows [16w, 16w+16)
    fx4 accx = (fx4){0.f, 0.f, 0.f, 0.f};
    #pragma unroll
    for (int ks = 0; ks < 8; ks++) {
      s16x8 bx = *(const s16x8*)(W3X + ((size_t)(ks * 4 + kc) * 16 + l15) * 8);
      accx = (ch == 0) ? MFMA(a3[0][ks], bx, accx) : MFMA(a3[1][ks], bx, accx);
    }
    if (l15 < 8) {
      float bias = b3[l15 * 65 + 64];
      #pragma unroll
      for (int rg = 0; rg < 4; rg++) {
        int row = w * 16 + kc * 4 + rg;
        v64_s[row * 8 + l15] = accx[rg] + bias;
      }
    }
  }
  bar_lds();  // H dead -> P usable; v64/xt visible

  // Linearized B addressing: per-lane base, stage stride 8192 B, nt*256 folds
  // into the load immediate. kp==3 reload = +65536 = next t's ks0 slab.
  const char* wp = (const char*)W3P + (size_t)(kc * 2048 + ch * 1024 + l15 * 16);

  s16x8 bA[4], bB[4];
  #pragma unroll
  for (int nt = 0; nt < 4; nt++) bA[nt] = *(const s16x8*)(wp + nt * 256);

  #pragma unroll 1
  for (int t = 0; t < 8; t++) {
    const char* wk = wp + (size_t)t * 65536;

    fx4 acc3[2][4];
    #pragma unroll
    for (int mi = 0; mi < 2; mi++)
      #pragma unroll
      for (int nt = 0; nt < 4; nt++) acc3[mi][nt] = (fx4){0.f, 0.f, 0.f, 0.f};

    // 2-deep WAR-bounded pipeline over ks: reload of a buffer sits AFTER the
    // MFMAs reading it -> compiler cannot hoist; max 32 live B regs.
    #pragma unroll
    for (int kp = 0; kp < 4; kp++) {
      const char* wk2 = wk + kp * 16384;
      #pragma unroll
      for (int nt = 0; nt < 4; nt++) bB[nt] = *(const s16x8*)(wk2 + 8192 + nt * 256);
      #pragma unroll
      for (int mi = 0; mi < 2; mi++)
        #pragma unroll
        for (int nt = 0; nt < 4; nt++) acc3[mi][nt] = MFMA(a3[mi][2 * kp], bA[nt], acc3[mi][nt]);
      if (kp < 3 || t < 7) {
        #pragma unroll
        for (int nt = 0; nt < 4; nt++) bA[nt] = *(const s16x8*)(wk2 + 16384 + nt * 256);
      }
      #pragma unroll
      for (int mi = 0; mi < 2; mi++)
        #pragma unroll
        for (int nt = 0; nt < 4; nt++) acc3[mi][nt] = MFMA(a3[mi][2 * kp + 1], bB[nt], acc3[mi][nt]);
    }

    bar_lds();  // A: postprocess(t-1) finished reading P

    // epilogue: wave w writes rows [32rh,+32) x cols [64ch,+64)
    #pragma unroll
    for (int nt = 0; nt < 4; nt++) {
      int nn = nt * 16 + l15;                       // 0..63 within the half
      float bias = ch ? b3[520 + t * 64 + nn] : b3[t * 65 + nn];
      int ci = ch ? (65 + nn) : nn;                 // hole at 64 (V65 in v64_s)
      #pragma unroll
      for (int mi = 0; mi < 2; mi++) {
        #pragma unroll
        for (int rg = 0; rg < 4; rg++) {
          int row = rh * 32 + mi * 16 + kc * 4 + rg;
          P[row * PSTR + ci] = acc3[mi][nt][rg] + bias;
        }
      }
    }

    bar_lds();  // B: params complete

    // ---------- postprocess channel t: 4 lanes/row, raw-sum algebra ----------
    // 3-pass softmax, NO wj[] array: scan recomputes exp(wr-wmax) from LDS.
    {
      int row = tid >> 2, sub = tid & 3;
      const float* prow = P + row * PSTR;
      const float* wrow = prow + 65 + sub * 16;
      float xtv = xt_s[row * 8 + t];

      // pass 1: wmax (transient float4s)
      float wmax;
      {
        float4 q0 = *(const float4*)(wrow + 0);
        float4 q1 = *(const float4*)(wrow + 4);
        float4 q2 = *(const float4*)(wrow + 8);
        float4 q3 = *(const float4*)(wrow + 12);
        float m0 = fmaxf(fmaxf(q0.x, q0.y), fmaxf(q0.z, q0.w));
        float m1 = fmaxf(fmaxf(q1.x, q1.y), fmaxf(q1.z, q1.w));
        float m2 = fmaxf(fmaxf(q2.x, q2.y), fmaxf(q2.z, q2.w));
        float m3 = fmaxf(fmaxf(q3.x, q3.y), fmaxf(q3.z, q3.w));
        wmax = fmaxf(fmaxf(m0, m1), fmaxf(m2, m3));
      }
      wmax = fmaxf(wmax, __shfl_xor(wmax, 1, 64));
      wmax = fmaxf(wmax, __shfl_xor(wmax, 2, 64));

      // pass 2: esum (transient)
      float esum = 0.0f;
      #pragma unroll
      for (int j = 0; j < 16; j++) esum += __expf(wrow[j] - wmax);

      int gbase = lane & ~3;
      float g0 = __shfl(esum, gbase + 0, 64);
      float g1 = __shfl(esum, gbase + 1, 64);
      float g2 = __shfl(esum, gbase + 2, 64);
      float g3 = __shfl(esum, gbase + 3, 64);
      float S = (g0 + g1) + (g2 + g3);
      float ebase = 0.0f;
      if (sub > 0) ebase += g0;
      if (sub > 1) ebase += g1;
      if (sub > 2) ebase += g2;
      float xs = xtv * S;   // compare raw cumsum against xt*S

      // pass 3: fused scan — ev stream + dl + prefix(cpart) + crossing capture
      float run = ebase;
      float evc = __expf(prow[sub * 16]);
      float evprev = evc, tlast = 0.0f;
      float dl = 0.0f, cpart = 0.0f;
      float wpadc = 0.0f, wbbc = 1.0f, evb = evc, evb1 = evc;
      int cnt = 0;
      #pragma unroll
      for (int j = 0; j < 16; j++) {
        float vr = (sub == 3 && j == 15) ? v64_s[row * 8 + t] : prow[sub * 16 + j + 1];
        float evn = __expf(vr);
        float wbj = __expf(wrow[j] - wmax);   // recompute (deterministic == pass 2)
        float nw = run + wbj;
        float term = (evc + evn) * wbj;
        bool le = (nw <= xs);
        bool hit = (!le) && (run <= xs);
        dl += term;
        if (le) { cpart += term; cnt++; }
        if (hit) { wpadc = run; wbbc = wbj; evb = evc; evb1 = evn; }
        tlast = term;
        evprev = evc;
        run = nw; evc = evn;
      }
      int bloc = (cnt < 16) ? (sub * 16 + cnt) : 64;
      int bmin = min(bloc, __shfl_xor(bloc, 1, 64));
      bmin = min(bmin, __shfl_xor(bmin, 2, 64));

      float d0 = __shfl(dl, gbase + 0, 64);
      float d1 = __shfl(dl, gbase + 1, 64);
      float d2 = __shfl(dl, gbase + 2, 64);
      float d3 = __shfl(dl, gbase + 3, 64);
      float dltot = (d0 + d1) + (d2 + d3);
      float cbase2 = 0.0f;
      if (sub > 0) cbase2 += d0;
      if (sub > 1) cbase2 += d1;
      if (sub > 2) cbase2 += d2;

      if (bmin == 64) {  // no strict crossing: continuous fallback b=63 (sub3 owns)
        wbbc = __expf(wrow[15] - wmax);
        wpadc = run - wbbc;
        evb = evprev; evb1 = evc;
        cpart = dl - tlast;
        bmin = 63;
      }

      if (sub == (bmin >> 4)) {
        float alpha = (xs - wpadc) / wbbc;          // invS cancels
        float Cnum = (alpha * (evb + 0.5f * alpha * (evb1 - evb))) * wbbc
                   + 0.5f * (cbase2 + cpart);
        out[(size_t)(r0 + row) * 16 + 2 * t + 1] = fminf(Cnum / (0.5f * dltot), 1.0f);
        float qn = evb + alpha * (evb1 - evb);
        float denomt = 0.5f * dltot / S;            // true denom
        lj_s[row * 8 + t] = __logf(qn) - __logf(denomt);
      }
    }
    // next epilogue is fenced by barA(t+1)
  }

  // ---- log_J = sum_t log(q_t): wave w emits its own 16 rows (intra-wave lj) ----
  if (lane < 16) {
    int row = w * 16 + lane;
    float s = 0.0f;
    #pragma unroll
    for (int t = 0; t < 8; t++) s += lj_s[row * 8 + t];
    out[(size_t)NROWS * 16 + r0 + row] = s;
  }
}

extern "C" void kernel_launch(void* const* d_in, const int* in_sizes, int n_in,
                              void* d_out, int out_size, void* d_ws, size_t ws_size,
                              hipStream_t stream) {
  const float* x  = (const float*)d_in[0];
  const float* W1 = (const float*)d_in[1];
  const float* b1 = (const float*)d_in[2];
  const float* W2 = (const float*)d_in[3];
  const float* b2 = (const float*)d_in[4];
  const float* W3 = (const float*)d_in[5];
  const float* b3 = (const float*)d_in[6];

  unsigned short* W12P = (unsigned short*)d_ws;                      // 4096 B
  float*          b12  = (float*)((char*)d_ws + 4096);               // 1024 B
  unsigned short* W3P  = (unsigned short*)((char*)d_ws + 5120);      // 524288 B
  unsigned short* W3X  = (unsigned short*)((char*)d_ws + 529408);    // 8192 B

  pack_weights<<<dim3(1049), dim3(256), 0, stream>>>(W1, b1, W2, b2, W3, W12P, b12, W3P, W3X);
  fused_pwquad<<<dim3(NROWS / BM), dim3(256), 0, stream>>>(
      x, b3, W12P, b12, W3P, W3X, (float*)d_out);
}

// Round 9
// 89.443 us; speedup vs baseline: 2.6266x; 1.0960x over previous
//
#include <hip/hip_runtime.h>

typedef short s16x8 __attribute__((ext_vector_type(8)));
typedef float fx4 __attribute__((ext_vector_type(4)));

#define NROWS 65536
#define PSTR 133   // params row stride (floats)

#define MFMA(a, b, c) __builtin_amdgcn_mfma_f32_16x16x32_bf16((a), (b), (c), 0, 0, 0)

__device__ __forceinline__ unsigned short f2bf(float f) {
  union { float f; unsigned u; } v; v.f = f;
  unsigned r = v.u + 0x7fffu + ((v.u >> 16) & 1u);  // RNE
  return (unsigned short)(r >> 16);
}

// ---------------------------------------------------------------------------
// Pack kernel (unchanged layouts).
//  blocks 0..1023   : W3P  idx=(((t*8+ks)*4+kc)*128+n)*8+e ; n<64 -> V col t*65+n,
//                     else W col 520+t*64+(n-64); value bf16(W3[k][c]), k=ks*32+kc*8+e
//  blocks 1024..1039: W3X  idx=((ks*4+kc)*16+n)*8+e ; n<8 -> V col n*65+64 else 0
//  blocks 1040..1047: W12 = W1@W2 (f32 acc -> bf16), B-frag order W12P[c*8+k]
//  block  1048      : b12 = b1@W2 + b2 (f32)
// ---------------------------------------------------------------------------
__global__ void pack_weights(const float* __restrict__ W1, const float* __restrict__ b1,
                             const float* __restrict__ W2, const float* __restrict__ b2,
                             const float* __restrict__ W3,
                             unsigned short* __restrict__ W12P, float* __restrict__ b12,
                             unsigned short* __restrict__ W3P, unsigned short* __restrict__ W3X) {
  int blk = blockIdx.x, tid = threadIdx.x;
  if (blk < 1024) {
    int i3 = blk * 256 + tid;
    int e = i3 & 7, n = (i3 >> 3) & 127, kc = (i3 >> 10) & 3, ks = (i3 >> 12) & 7, t = i3 >> 15;
    int k = ks * 32 + kc * 8 + e;
    int c = (n < 64) ? (t * 65 + n) : (520 + t * 64 + (n - 64));
    W3P[i3] = f2bf(W3[k * 1032 + c]);
  } else if (blk < 1040) {
    int ix = (blk - 1024) * 256 + tid;
    int e = ix & 7, n = (ix >> 3) & 15, kc = (ix >> 7) & 3, ks = ix >> 9;
    int k = ks * 32 + kc * 8 + e;
    float v = (n < 8) ? W3[k * 1032 + n * 65 + 64] : 0.0f;
    W3X[ix] = f2bf(v);
  } else if (blk < 1048) {
    int k = blk - 1040, c = tid;
    float s = 0.0f;
    for (int m = 0; m < 256; m++) s += W1[k * 256 + m] * W2[m * 256 + c];
    W12P[c * 8 + k] = f2bf(s);
  } else {
    int c = tid;
    float s = b2[c];
    for (int m = 0; m < 256; m++) s += b1[m] * W2[m * 256 + c];
    b12[c] = s;
  }
}

// ---------------------------------------------------------------------------
// BARRIER-FREE fused kernel: 1 wave per block, 32 rows per wave, 2048 blocks.
// Every phase touches only this wave's 32 rows -> zero s_barrier; intra-wave
// LDS ordering (program order + lgkmcnt) is the only sync needed.
// 8 blocks/CU by LDS (20096 B); (64,2) -> 256-VGPR budget, no spill (R8 verified).
// a3[2][8] + acc3[2][8] in AGPRs; B WAR-bounded bA/bB (32 arch regs max).
// R9 FIX: cross-t B prefetch at ks==7 was wk2+8192+57344 = (t+1,ks=7) slab --
// WRONG; correct target (t+1,ks=0) = wk+65536 = wk2+8192, identical to the
// intra-t reload -> branches merged into (ks<7 || t<7).
// LDS map (per block = per wave):
//   P  [0,17024)       : params f32 [32][133]; h bf16 [32][256] swizzled aliases it
//   xt [17024,18048)   : [32][8] f32
//   v64[18048,19072)   : [32][8] f32
//   lj [19072,20096)   : [32][8] f32 ; XC bf16 [32][8] aliases (dead before lj)
// ---------------------------------------------------------------------------
__global__ __launch_bounds__(64, 2) void fused_pwquad(
    const float* __restrict__ x, const float* __restrict__ b3,
    const unsigned short* __restrict__ W12P, const float* __restrict__ b12,
    const unsigned short* __restrict__ W3P, const unsigned short* __restrict__ W3X,
    float* __restrict__ out)
{
  __shared__ char smem[20096];
  char*  H     = smem;                 // aliases P
  float* P     = (float*)smem;
  float* xt_s  = (float*)(smem + 17024);
  float* v64_s = (float*)(smem + 18048);
  float* lj_s  = (float*)(smem + 19072);
  char*  XC    = smem + 19072;         // aliases lj (XC dead before lj writes)

  const int lane = threadIdx.x & 63;
  const int kc   = lane >> 4;
  const int l15  = lane & 15;
  const int r0   = blockIdx.x * 32;

  // ---- phase 0: load 32 rows of x; emit copied (even) z cols; stash xc/xt ----
  {
    const float4* xin = (const float4*)(x + (size_t)r0 * 16);
    #pragma unroll
    for (int i = 0; i < 2; i++) {
      int f = i * 64 + lane;           // 0..127 float4s, coalesced
      float4 v = xin[f];
      int row = f >> 2, q = f & 3;
      out[(size_t)(r0 + row) * 16 + 4 * q + 0] = fminf(v.x, 1.0f);
      out[(size_t)(r0 + row) * 16 + 4 * q + 2] = fminf(v.z, 1.0f);
      unsigned pk = (unsigned)f2bf(v.x) | ((unsigned)f2bf(v.z) << 16);
      *(unsigned*)(XC + row * 16 + q * 4) = pk;
      float2 t2; t2.x = v.y; t2.y = v.w;
      *(float2*)(xt_s + row * 8 + 2 * q) = t2;
    }
  }

  // ---- GEMM-h: h = relu(xc @ W12 + b12), 32 rows x 256 cols, K=8 ----
  {
    s16x8 ah[2] = {};
    if (kc == 0) {
      #pragma unroll
      for (int mi = 0; mi < 2; mi++) ah[mi] = *(const s16x8*)(XC + (mi * 16 + l15) * 16);
    }
    #pragma unroll
    for (int c = 0; c < 4; c++) {       // 4 col-chunks of 64
      s16x8 bh[4];
      #pragma unroll
      for (int nt = 0; nt < 4; nt++)
        bh[nt] = *(const s16x8*)(W12P + (size_t)(c * 64 + nt * 16 + l15) * 8);
      fx4 acc[2][4];
      #pragma unroll
      for (int mi = 0; mi < 2; mi++)
        #pragma unroll
        for (int nt = 0; nt < 4; nt++) acc[mi][nt] = (fx4){0.f, 0.f, 0.f, 0.f};
      #pragma unroll
      for (int mi = 0; mi < 2; mi++)
        #pragma unroll
        for (int nt = 0; nt < 4; nt++) acc[mi][nt] = MFMA(ah[mi], bh[nt], acc[mi][nt]);
      #pragma unroll
      for (int nt = 0; nt < 4; nt++) {
        int col = c * 64 + nt * 16 + l15;
        float bias = b12[col];
        #pragma unroll
        for (int mi = 0; mi < 2; mi++) {
          #pragma unroll
          for (int rg = 0; rg < 4; rg++) {
            int row = mi * 16 + kc * 4 + rg;
            float v = fmaxf(acc[mi][nt][rg] + bias, 0.0f);
            int byte = (row << 9) + (col << 1);
            byte ^= ((row & 7) << 4);
            *(unsigned short*)(H + byte) = f2bf(v);
          }
        }
      }
    }
  }

  // ---- hoist A-frags (own 32 rows, all K); V65 GEMM ----
  s16x8 a3[2][8];
  #pragma unroll
  for (int mi = 0; mi < 2; mi++) {
    #pragma unroll
    for (int ks = 0; ks < 8; ks++) {
      int row = mi * 16 + l15;
      int byte = (row << 9) + ks * 64 + (kc << 4);
      byte ^= ((row & 7) << 4);
      a3[mi][ks] = *(const s16x8*)(H + byte);
    }
  }
  {
    fx4 ax0 = (fx4){0.f, 0.f, 0.f, 0.f}, ax1 = ax0;
    #pragma unroll
    for (int ks = 0; ks < 8; ks++) {
      s16x8 bx = *(const s16x8*)(W3X + ((size_t)(ks * 4 + kc) * 16 + l15) * 8);
      ax0 = MFMA(a3[0][ks], bx, ax0);
      ax1 = MFMA(a3[1][ks], bx, ax1);
    }
    if (l15 < 8) {
      float bias = b3[l15 * 65 + 64];
      #pragma unroll
      for (int rg = 0; rg < 4; rg++) {
        v64_s[(kc * 4 + rg) * 8 + l15]      = ax0[rg] + bias;
        v64_s[(16 + kc * 4 + rg) * 8 + l15] = ax1[rg] + bias;
      }
    }
  }
  // H dead from here -> P reuses the space (same wave: ordering guaranteed)

  // per-lane B base; (t,ks) slab = +t*65536 + ks*8192; V tiles at +nt*256,
  // W tiles at +1024+nt*256
  const char* wp = (const char*)W3P + (size_t)(kc * 2048 + l15 * 16);

  s16x8 bA[4], bB[4];
  #pragma unroll
  for (int nt = 0; nt < 4; nt++) bA[nt] = *(const s16x8*)(wp + nt * 256);

  #pragma unroll 1
  for (int t = 0; t < 8; t++) {
    const char* wk = wp + (size_t)t * 65536;

    fx4 acc3[2][8];
    #pragma unroll
    for (int mi = 0; mi < 2; mi++)
      #pragma unroll
      for (int nt = 0; nt < 8; nt++) acc3[mi][nt] = (fx4){0.f, 0.f, 0.f, 0.f};

    // WAR-bounded 2-buffer stream over ks: reload sits AFTER the MFMAs reading
    // the buffer -> compiler cannot hoist; max 32 live B regs.
    // wk2+8192 is BOTH "(t, ks+1) V-half" and, at ks==7, "(t+1, ks=0) V-half".
    #pragma unroll
    for (int ks = 0; ks < 8; ks++) {
      const char* wk2 = wk + ks * 8192;
      #pragma unroll
      for (int nt = 0; nt < 4; nt++) bB[nt] = *(const s16x8*)(wk2 + 1024 + nt * 256);
      #pragma unroll
      for (int mi = 0; mi < 2; mi++)
        #pragma unroll
        for (int nt = 0; nt < 4; nt++) acc3[mi][nt] = MFMA(a3[mi][ks], bA[nt], acc3[mi][nt]);
      if (ks < 7 || t < 7) {
        #pragma unroll
        for (int nt = 0; nt < 4; nt++) bA[nt] = *(const s16x8*)(wk2 + 8192 + nt * 256);
      }
      #pragma unroll
      for (int mi = 0; mi < 2; mi++)
        #pragma unroll
        for (int nt = 0; nt < 4; nt++) acc3[mi][nt + 4] = MFMA(a3[mi][ks], bB[nt], acc3[mi][nt + 4]);
    }

    // epilogue: own 32 rows x 128 cols -> P (wave-private, no barrier)
    #pragma unroll
    for (int nt = 0; nt < 8; nt++) {
      int nn = nt * 16 + l15;                       // 0..127 within channel t
      bool isV = (nt < 4);
      float bias = isV ? b3[t * 65 + nn] : b3[520 + t * 64 + (nn - 64)];
      int ci = isV ? nn : (nn + 1);                 // hole at 64 (V65 in v64_s)
      #pragma unroll
      for (int mi = 0; mi < 2; mi++) {
        #pragma unroll
        for (int rg = 0; rg < 4; rg++) {
          int row = mi * 16 + kc * 4 + rg;
          P[row * PSTR + ci] = acc3[mi][nt][rg] + bias;
        }
      }
    }

    // ---------- postprocess channel t: 2 lanes/row, 32-bin scans ----------
    {
      int rowl = lane >> 1, sub = lane & 1;
      const float* prow = P + rowl * PSTR;
      const float* wrow = prow + 65 + sub * 32;
      float xtv = xt_s[rowl * 8 + t];

      // softmax numerators (kept in regs; live only here)
      float wj[32];
      float wmax = -3.0e38f;
      #pragma unroll
      for (int i = 0; i < 8; i++) {
        float4 v4 = *(const float4*)(wrow + 4 * i);
        wj[4*i] = v4.x; wj[4*i+1] = v4.y; wj[4*i+2] = v4.z; wj[4*i+3] = v4.w;
        wmax = fmaxf(wmax, fmaxf(fmaxf(v4.x, v4.y), fmaxf(v4.z, v4.w)));
      }
      wmax = fmaxf(wmax, __shfl_xor(wmax, 1, 64));

      float esum = 0.0f;
      #pragma unroll
      for (int j = 0; j < 32; j++) { wj[j] = __expf(wj[j] - wmax); esum += wj[j]; }

      float eoth = __shfl_xor(esum, 1, 64);
      float S = esum + eoth;
      float ebase = sub ? eoth : 0.0f;
      float xs = xtv * S;                 // raw-cumsum space crossing threshold

      // fused scan: ev stream + dl + prefix(cpart) + crossing capture
      float run = ebase;
      float evc = __expf(prow[sub * 32]);
      float evprev = evc, tlast = 0.0f;
      float dl = 0.0f, cpart = 0.0f;
      float wpadc = 0.0f, wbbc = 1.0f, evb = evc, evb1 = evc;
      int cnt = 0;
      #pragma unroll
      for (int j = 0; j < 32; j++) {
        float vr = (sub == 1 && j == 31) ? v64_s[rowl * 8 + t] : prow[sub * 32 + j + 1];
        float evn = __expf(vr);
        float wbj = wj[j];
        float nw = run + wbj;
        float term = (evc + evn) * wbj;
        bool le = (nw <= xs);
        bool hit = (!le) && (run <= xs);
        dl += term;
        if (le) { cpart += term; cnt++; }
        if (hit) { wpadc = run; wbbc = wbj; evb = evc; evb1 = evn; }
        tlast = term;
        evprev = evc;
        run = nw; evc = evn;
      }
      int bloc = (cnt < 32) ? (sub * 32 + cnt) : 64;
      int bmin = min(bloc, __shfl_xor(bloc, 1, 64));

      float doth = __shfl_xor(dl, 1, 64);
      float dltot = dl + doth;
      float cbase2 = sub ? doth : 0.0f;

      if (bmin == 64) {  // no strict crossing: continuous fallback b=63 (sub1 owns)
        wbbc = wj[31];
        wpadc = run - wbbc;
        evb = evprev; evb1 = evc;
        cpart = dl - tlast;
        bmin = 63;
      }

      if (sub == (bmin >> 5)) {
        float alpha = (xs - wpadc) / wbbc;          // softmax scale cancels
        float Cnum = (alpha * (evb + 0.5f * alpha * (evb1 - evb))) * wbbc
                   + 0.5f * (cbase2 + cpart);
        out[(size_t)(r0 + rowl) * 16 + 2 * t + 1] = fminf(Cnum / (0.5f * dltot), 1.0f);
        float qn = evb + alpha * (evb1 - evb);
        float denomt = 0.5f * dltot / S;            // true denominator
        lj_s[rowl * 8 + t] = __logf(qn) - __logf(denomt);
      }
    }
    // next t's epilogue writes P again -- same wave, program-ordered; safe
  }

  // ---- log_J = sum_t log(q_t) for own 32 rows ----
  if (lane < 32) {
    float s = 0.0f;
    #pragma unroll
    for (int t = 0; t < 8; t++) s += lj_s[lane * 8 + t];
    out[(size_t)NROWS * 16 + r0 + lane] = s;
  }
}

extern "C" void kernel_launch(void* const* d_in, const int* in_sizes, int n_in,
                              void* d_out, int out_size, void* d_ws, size_t ws_size,
                              hipStream_t stream) {
  const float* x  = (const float*)d_in[0];
  const float* W1 = (const float*)d_in[1];
  const float* b1 = (const float*)d_in[2];
  const float* W2 = (const float*)d_in[3];
  const float* b2 = (const float*)d_in[4];
  const float* W3 = (const float*)d_in[5];
  const float* b3 = (const float*)d_in[6];

  unsigned short* W12P = (unsigned short*)d_ws;                      // 4096 B
  float*          b12  = (float*)((char*)d_ws + 4096);               // 1024 B
  unsigned short* W3P  = (unsigned short*)((char*)d_ws + 5120);      // 524288 B
  unsigned short* W3X  = (unsigned short*)((char*)d_ws + 529408);    // 8192 B

  pack_weights<<<dim3(1049), dim3(256), 0, stream>>>(W1, b1, W2, b2, W3, W12P, b12, W3P, W3X);
  fused_pwquad<<<dim3(NROWS / 32), dim3(64), 0, stream>>>(
      x, b3, W12P, b12, W3P, W3X, (float*)d_out);
}

// Round 10
// 70.396 us; speedup vs baseline: 3.3373x; 1.2706x over previous
//
#include <hip/hip_runtime.h>

typedef short s16x8 __attribute__((ext_vector_type(8)));
typedef float fx4 __attribute__((ext_vector_type(4)));

#define NROWS 65536
#define PSTR 133   // params row stride (floats); odd -> conflict-free LDS reads

#define MFMA(a, b, c) __builtin_amdgcn_mfma_f32_16x16x32_bf16((a), (b), (c), 0, 0, 0)

__device__ __forceinline__ unsigned short f2bf(float f) {
  union { float f; unsigned u; } v; v.f = f;
  unsigned r = v.u + 0x7fffu + ((v.u >> 16) & 1u);  // RNE
  return (unsigned short)(r >> 16);
}

// ---------------------------------------------------------------------------
// Pack kernel (unchanged layouts).
//  blocks 0..1023   : W3P  idx=(((t*8+ks)*4+kc)*128+n)*8+e ; n<64 -> V col t*65+n,
//                     else W col 520+t*64+(n-64); value bf16(W3[k][c]), k=ks*32+kc*8+e
//  blocks 1024..1039: W3X  idx=((ks*4+kc)*16+n)*8+e ; n<8 -> V col n*65+64 else 0
//  blocks 1040..1047: W12 = W1@W2 (f32 acc -> bf16), B-frag order W12P[c*8+k]
//  block  1048      : b12 = b1@W2 + b2 (f32)
// ---------------------------------------------------------------------------
__global__ void pack_weights(const float* __restrict__ W1, const float* __restrict__ b1,
                             const float* __restrict__ W2, const float* __restrict__ b2,
                             const float* __restrict__ W3,
                             unsigned short* __restrict__ W12P, float* __restrict__ b12,
                             unsigned short* __restrict__ W3P, unsigned short* __restrict__ W3X) {
  int blk = blockIdx.x, tid = threadIdx.x;
  if (blk < 1024) {
    int i3 = blk * 256 + tid;
    int e = i3 & 7, n = (i3 >> 3) & 127, kc = (i3 >> 10) & 3, ks = (i3 >> 12) & 7, t = i3 >> 15;
    int k = ks * 32 + kc * 8 + e;
    int c = (n < 64) ? (t * 65 + n) : (520 + t * 64 + (n - 64));
    W3P[i3] = f2bf(W3[k * 1032 + c]);
  } else if (blk < 1040) {
    int ix = (blk - 1024) * 256 + tid;
    int e = ix & 7, n = (ix >> 3) & 15, kc = (ix >> 7) & 3, ks = ix >> 9;
    int k = ks * 32 + kc * 8 + e;
    float v = (n < 8) ? W3[k * 1032 + n * 65 + 64] : 0.0f;
    W3X[ix] = f2bf(v);
  } else if (blk < 1048) {
    int k = blk - 1040, c = tid;
    float s = 0.0f;
    for (int m = 0; m < 256; m++) s += W1[k * 256 + m] * W2[m * 256 + c];
    W12P[c * 8 + k] = f2bf(s);
  } else {
    int c = tid;
    float s = b2[c];
    for (int m = 0; m < 256; m++) s += b1[m] * W2[m * 256 + c];
    b12[c] = s;
  }
}

// ---------------------------------------------------------------------------
// BARRIER-FREE fused kernel: 1 wave per block, 32 rows per wave, 2048 blocks.
// R10 changes vs R9 (both latency-stall fixes, same structure):
//  (a) B pipeline: 4 quads A0/B0 (even ks) + A1/B1 (odd ks); every load issued
//      one full round ahead (and across the epilogue+postprocess at t-boundary).
//      WAR-bounded -> max 64 live B regs, no v_movs.
//  (b) Postprocess scan: V-stream via 4-deep rotating fx4 qv[] (16 regs),
//      reads issued ~3 groups ahead -> scan is pure-register (no per-iter LDS).
//  (c) s_setprio(1) around MFMA clusters (2 indep waves/SIMD -> role diversity).
// LDS map (per block = per wave):
//   P  [0,17024)       : params f32 [32][133]; h bf16 [32][256] swizzled aliases it
//   xt [17024,18048)   : [32][8] f32
//   v64[18048,19072)   : [32][8] f32
//   lj [19072,20096)   : [32][8] f32 ; XC bf16 [32][8] aliases (dead before lj)
// ---------------------------------------------------------------------------
__global__ __launch_bounds__(64, 2) void fused_pwquad(
    const float* __restrict__ x, const float* __restrict__ b3,
    const unsigned short* __restrict__ W12P, const float* __restrict__ b12,
    const unsigned short* __restrict__ W3P, const unsigned short* __restrict__ W3X,
    float* __restrict__ out)
{
  __shared__ char smem[20096];
  char*  H     = smem;                 // aliases P
  float* P     = (float*)smem;
  float* xt_s  = (float*)(smem + 17024);
  float* v64_s = (float*)(smem + 18048);
  float* lj_s  = (float*)(smem + 19072);
  char*  XC    = smem + 19072;         // aliases lj (XC dead before lj writes)

  const int lane = threadIdx.x & 63;
  const int kc   = lane >> 4;
  const int l15  = lane & 15;
  const int r0   = blockIdx.x * 32;

  // ---- phase 0: load 32 rows of x; emit copied (even) z cols; stash xc/xt ----
  {
    const float4* xin = (const float4*)(x + (size_t)r0 * 16);
    #pragma unroll
    for (int i = 0; i < 2; i++) {
      int f = i * 64 + lane;           // 0..127 float4s, coalesced
      float4 v = xin[f];
      int row = f >> 2, q = f & 3;
      out[(size_t)(r0 + row) * 16 + 4 * q + 0] = fminf(v.x, 1.0f);
      out[(size_t)(r0 + row) * 16 + 4 * q + 2] = fminf(v.z, 1.0f);
      unsigned pk = (unsigned)f2bf(v.x) | ((unsigned)f2bf(v.z) << 16);
      *(unsigned*)(XC + row * 16 + q * 4) = pk;
      float2 t2; t2.x = v.y; t2.y = v.w;
      *(float2*)(xt_s + row * 8 + 2 * q) = t2;
    }
  }

  // ---- GEMM-h: h = relu(xc @ W12 + b12), 32 rows x 256 cols, K=8 ----
  {
    s16x8 ah[2] = {};
    if (kc == 0) {
      #pragma unroll
      for (int mi = 0; mi < 2; mi++) ah[mi] = *(const s16x8*)(XC + (mi * 16 + l15) * 16);
    }
    #pragma unroll
    for (int c = 0; c < 4; c++) {       // 4 col-chunks of 64
      s16x8 bh[4];
      #pragma unroll
      for (int nt = 0; nt < 4; nt++)
        bh[nt] = *(const s16x8*)(W12P + (size_t)(c * 64 + nt * 16 + l15) * 8);
      fx4 acc[2][4];
      #pragma unroll
      for (int mi = 0; mi < 2; mi++)
        #pragma unroll
        for (int nt = 0; nt < 4; nt++) acc[mi][nt] = (fx4){0.f, 0.f, 0.f, 0.f};
      #pragma unroll
      for (int mi = 0; mi < 2; mi++)
        #pragma unroll
        for (int nt = 0; nt < 4; nt++) acc[mi][nt] = MFMA(ah[mi], bh[nt], acc[mi][nt]);
      #pragma unroll
      for (int nt = 0; nt < 4; nt++) {
        int col = c * 64 + nt * 16 + l15;
        float bias = b12[col];
        #pragma unroll
        for (int mi = 0; mi < 2; mi++) {
          #pragma unroll
          for (int rg = 0; rg < 4; rg++) {
            int row = mi * 16 + kc * 4 + rg;
            float v = fmaxf(acc[mi][nt][rg] + bias, 0.0f);
            int byte = (row << 9) + (col << 1);
            byte ^= ((row & 7) << 4);
            *(unsigned short*)(H + byte) = f2bf(v);
          }
        }
      }
    }
  }

  // ---- hoist A-frags (own 32 rows, all K); V65 GEMM ----
  s16x8 a3[2][8];
  #pragma unroll
  for (int mi = 0; mi < 2; mi++) {
    #pragma unroll
    for (int ks = 0; ks < 8; ks++) {
      int row = mi * 16 + l15;
      int byte = (row << 9) + ks * 64 + (kc << 4);
      byte ^= ((row & 7) << 4);
      a3[mi][ks] = *(const s16x8*)(H + byte);
    }
  }
  {
    fx4 ax0 = (fx4){0.f, 0.f, 0.f, 0.f}, ax1 = ax0;
    #pragma unroll
    for (int ks = 0; ks < 8; ks++) {
      s16x8 bx = *(const s16x8*)(W3X + ((size_t)(ks * 4 + kc) * 16 + l15) * 8);
      ax0 = MFMA(a3[0][ks], bx, ax0);
      ax1 = MFMA(a3[1][ks], bx, ax1);
    }
    if (l15 < 8) {
      float bias = b3[l15 * 65 + 64];
      #pragma unroll
      for (int rg = 0; rg < 4; rg++) {
        v64_s[(kc * 4 + rg) * 8 + l15]      = ax0[rg] + bias;
        v64_s[(16 + kc * 4 + rg) * 8 + l15] = ax1[rg] + bias;
      }
    }
  }
  // H dead from here -> P reuses the space (same wave: ordering guaranteed)

  // per-lane B base; (t,ks) slab = +t*65536 + ks*8192; V tiles at +nt*256,
  // W tiles at +1024+nt*256
  const char* wp = (const char*)W3P + (size_t)(kc * 2048 + l15 * 16);

  // 4-quad pipeline: A0/B0 serve even ks, A1/B1 odd ks; each loaded 1 round ahead
  s16x8 A0[4], B0[4], A1[4], B1[4];
  #pragma unroll
  for (int nt = 0; nt < 4; nt++) {
    A0[nt] = *(const s16x8*)(wp + nt * 256);
    B0[nt] = *(const s16x8*)(wp + 1024 + nt * 256);
  }

  #pragma unroll 1
  for (int t = 0; t < 8; t++) {
    const char* wk = wp + (size_t)t * 65536;

    fx4 acc3[2][8];
    #pragma unroll
    for (int mi = 0; mi < 2; mi++)
      #pragma unroll
      for (int nt = 0; nt < 8; nt++) acc3[mi][nt] = (fx4){0.f, 0.f, 0.f, 0.f};

    #pragma unroll
    for (int kp = 0; kp < 4; kp++) {
      const char* e0 = wk + kp * 16384;      // even round (ks=2kp) base
      // even round: consume A0/B0, prefetch odd round (ks=2kp+1)
      #pragma unroll
      for (int nt = 0; nt < 4; nt++) {
        A1[nt] = *(const s16x8*)(e0 + 8192 + nt * 256);
        B1[nt] = *(const s16x8*)(e0 + 8192 + 1024 + nt * 256);
      }
      __builtin_amdgcn_s_setprio(1);
      #pragma unroll
      for (int mi = 0; mi < 2; mi++)
        #pragma unroll
        for (int nt = 0; nt < 4; nt++) {
          acc3[mi][nt]     = MFMA(a3[mi][2 * kp], A0[nt], acc3[mi][nt]);
          acc3[mi][nt + 4] = MFMA(a3[mi][2 * kp], B0[nt], acc3[mi][nt + 4]);
        }
      __builtin_amdgcn_s_setprio(0);
      // odd round: consume A1/B1, prefetch next even round (ks=2kp+2; at kp==3
      // this is exactly (t+1, ks=0): wk + 65536)
      if (kp < 3 || t < 7) {
        #pragma unroll
        for (int nt = 0; nt < 4; nt++) {
          A0[nt] = *(const s16x8*)(e0 + 16384 + nt * 256);
          B0[nt] = *(const s16x8*)(e0 + 16384 + 1024 + nt * 256);
        }
      }
      __builtin_amdgcn_s_setprio(1);
      #pragma unroll
      for (int mi = 0; mi < 2; mi++)
        #pragma unroll
        for (int nt = 0; nt < 4; nt++) {
          acc3[mi][nt]     = MFMA(a3[mi][2 * kp + 1], A1[nt], acc3[mi][nt]);
          acc3[mi][nt + 4] = MFMA(a3[mi][2 * kp + 1], B1[nt], acc3[mi][nt + 4]);
        }
      __builtin_amdgcn_s_setprio(0);
    }

    // epilogue: own 32 rows x 128 cols -> P (wave-private, no barrier)
    #pragma unroll
    for (int nt = 0; nt < 8; nt++) {
      int nn = nt * 16 + l15;                       // 0..127 within channel t
      bool isV = (nt < 4);
      float bias = isV ? b3[t * 65 + nn] : b3[520 + t * 64 + (nn - 64)];
      int ci = isV ? nn : (nn + 1);                 // hole at 64 (V65 in v64_s)
      #pragma unroll
      for (int mi = 0; mi < 2; mi++) {
        #pragma unroll
        for (int rg = 0; rg < 4; rg++) {
          int row = mi * 16 + kc * 4 + rg;
          P[row * PSTR + ci] = acc3[mi][nt][rg] + bias;
        }
      }
    }

    // ---------- postprocess channel t: 2 lanes/row, 32-bin scans ----------
    {
      int rowl = lane >> 1, sub = lane & 1;
      const float* prow = P + rowl * PSTR;
      const float* wrow = prow + 65 + sub * 32;
      const float* vrow = prow + sub * 32;
      float xtv = xt_s[rowl * 8 + t];

      // softmax numerators (kept in regs; live only here)
      float wj[32];
      float wmax = -3.0e38f;
      #pragma unroll
      for (int i = 0; i < 8; i++) {
        fx4 v4 = *(const fx4*)(wrow + 4 * i);
        wj[4*i] = v4[0]; wj[4*i+1] = v4[1]; wj[4*i+2] = v4[2]; wj[4*i+3] = v4[3];
        wmax = fmaxf(wmax, fmaxf(fmaxf(v4[0], v4[1]), fmaxf(v4[2], v4[3])));
      }
      wmax = fmaxf(wmax, __shfl_xor(wmax, 1, 64));

      float esum = 0.0f;
      #pragma unroll
      for (int j = 0; j < 32; j++) { wj[j] = __expf(wj[j] - wmax); esum += wj[j]; }

      float eoth = __shfl_xor(esum, 1, 64);
      float S = esum + eoth;
      float ebase = sub ? eoth : 0.0f;
      float xs = xtv * S;                 // raw-cumsum space crossing threshold

      // V-stream via 4-deep rotating fx4 buffer (reads ~3 groups ahead)
      fx4 qv[4];
      qv[0] = *(const fx4*)(vrow + 0);
      qv[1] = *(const fx4*)(vrow + 4);
      qv[2] = *(const fx4*)(vrow + 8);
      float vv32 = (sub == 1) ? v64_s[rowl * 8 + t] : prow[32];

      float run = ebase;
      float evc = __expf(qv[0][0]);
      float evprev = evc, tlast = 0.0f;
      float dl = 0.0f, cpart = 0.0f;
      float wpadc = 0.0f, wbbc = 1.0f, evb = evc, evb1 = evc;
      int cnt = 0;
      #pragma unroll
      for (int i = 0; i < 8; i++) {
        if (i < 5) qv[(i + 3) & 3] = *(const fx4*)(vrow + 4 * (i + 3));
        #pragma unroll
        for (int jj = 0; jj < 4; jj++) {
          int j = 4 * i + jj;
          float vr = (jj < 3) ? qv[i & 3][jj + 1]
                              : ((i < 7) ? qv[(i + 1) & 3][0] : vv32);
          float evn = __expf(vr);
          float wbj = wj[j];
          float nw = run + wbj;
          float term = (evc + evn) * wbj;
          bool le = (nw <= xs);
          bool hit = (!le) && (run <= xs);
          dl += term;
          if (le) { cpart += term; cnt++; }
          if (hit) { wpadc = run; wbbc = wbj; evb = evc; evb1 = evn; }
          tlast = term;
          evprev = evc;
          run = nw; evc = evn;
        }
      }
      int bloc = (cnt < 32) ? (sub * 32 + cnt) : 64;
      int bmin = min(bloc, __shfl_xor(bloc, 1, 64));

      float doth = __shfl_xor(dl, 1, 64);
      float dltot = dl + doth;
      float cbase2 = sub ? doth : 0.0f;

      if (bmin == 64) {  // no strict crossing: continuous fallback b=63 (sub1 owns)
        wbbc = wj[31];
        wpadc = run - wbbc;
        evb = evprev; evb1 = evc;
        cpart = dl - tlast;
        bmin = 63;
      }

      if (sub == (bmin >> 5)) {
        float alpha = (xs - wpadc) / wbbc;          // softmax scale cancels
        float Cnum = (alpha * (evb + 0.5f * alpha * (evb1 - evb))) * wbbc
                   + 0.5f * (cbase2 + cpart);
        out[(size_t)(r0 + rowl) * 16 + 2 * t + 1] = fminf(Cnum / (0.5f * dltot), 1.0f);
        float qn = evb + alpha * (evb1 - evb);
        float denomt = 0.5f * dltot / S;            // true denominator
        lj_s[rowl * 8 + t] = __logf(qn) - __logf(denomt);
      }
    }
    // next t's epilogue writes P again -- same wave, program-ordered; safe
  }

  // ---- log_J = sum_t log(q_t) for own 32 rows ----
  if (lane < 32) {
    float s = 0.0f;
    #pragma unroll
    for (int t = 0; t < 8; t++) s += lj_s[lane * 8 + t];
    out[(size_t)NROWS * 16 + r0 + lane] = s;
  }
}

extern "C" void kernel_launch(void* const* d_in, const int* in_sizes, int n_in,
                              void* d_out, int out_size, void* d_ws, size_t ws_size,
                              hipStream_t stream) {
  const float* x  = (const float*)d_in[0];
  const float* W1 = (const float*)d_in[1];
  const float* b1 = (const float*)d_in[2];
  const float* W2 = (const float*)d_in[3];
  const float* b2 = (const float*)d_in[4];
  const float* W3 = (const float*)d_in[5];
  const float* b3 = (const float*)d_in[6];

  unsigned short* W12P = (unsigned short*)d_ws;                      // 4096 B
  float*          b12  = (float*)((char*)d_ws + 4096);               // 1024 B
  unsigned short* W3P  = (unsigned short*)((char*)d_ws + 5120);      // 524288 B
  unsigned short* W3X  = (unsigned short*)((char*)d_ws + 529408);    // 8192 B

  pack_weights<<<dim3(1049), dim3(256), 0, stream>>>(W1, b1, W2, b2, W3, W12P, b12, W3P, W3X);
  fused_pwquad<<<dim3(NROWS / 32), dim3(64), 0, stream>>>(
      x, b3, W12P, b12, W3P, W3X, (float*)d_out);
}

// Round 11
// 62.180 us; speedup vs baseline: 3.7783x; 1.1321x over previous
//
#include <hip/hip_runtime.h>

typedef short s16x8 __attribute__((ext_vector_type(8)));
typedef float fx4 __attribute__((ext_vector_type(4)));

#define NROWS 65536

#define MFMA(a, b, c) __builtin_amdgcn_mfma_f32_16x16x32_bf16((a), (b), (c), 0, 0, 0)

__device__ __forceinline__ unsigned short f2bf(float f) {
  union { float f; unsigned u; } v; v.f = f;
  unsigned r = v.u + 0x7fffu + ((v.u >> 16) & 1u);  // RNE
  return (unsigned short)(r >> 16);
}

// ---------------------------------------------------------------------------
// Pack kernel.
//  blocks 0..1023   : W3Q — W3 packed as MFMA *A*-fragments for the TRANSPOSED
//    GEMM3 (P^T = W3·h^T). idx=(((t*8+ks)*8+nti)*64+lane)*8+e ; lane=(kc<<4)|m ;
//    k = ks*32+kc*8+e ; m -> bin perm: g=m>>2, rg=m&3:
//      nti<4 : c = t*65 + (16g + nti*4 + rg)          (V bins)
//      nti>=4: c = 520 + t*64 + (16g + (nti-4)*4 + rg) (W bins)
//    => output lane-group g owns V[16g,+16) and W[16g,+16) of its row, in order.
//  blocks 1024..1039: W3X  idx=((ks*4+kc)*16+n)*8+e ; n<8 -> V col n*65+64 else 0
//  blocks 1040..1047: W12 = W1@W2 (f32 acc -> bf16), B-frag order W12P[c*8+k]
//  block  1048      : b12 = b1@W2 + b2 (f32)
// ---------------------------------------------------------------------------
__global__ void pack_weights(const float* __restrict__ W1, const float* __restrict__ b1,
                             const float* __restrict__ W2, const float* __restrict__ b2,
                             const float* __restrict__ W3,
                             unsigned short* __restrict__ W12P, float* __restrict__ b12,
                             unsigned short* __restrict__ W3Q, unsigned short* __restrict__ W3X) {
  int blk = blockIdx.x, tid = threadIdx.x;
  if (blk < 1024) {
    int i3 = blk * 256 + tid;
    int e = i3 & 7, lane = (i3 >> 3) & 63, nti = (i3 >> 9) & 7, ks = (i3 >> 12) & 7, t = i3 >> 15;
    int m = lane & 15, kc = lane >> 4;
    int k = ks * 32 + kc * 8 + e;
    int g = m >> 2, rg = m & 3;
    int c = (nti < 4) ? (t * 65 + 16 * g + nti * 4 + rg)
                      : (520 + t * 64 + 16 * g + (nti - 4) * 4 + rg);
    W3Q[i3] = f2bf(W3[k * 1032 + c]);
  } else if (blk < 1040) {
    int ix = (blk - 1024) * 256 + tid;
    int e = ix & 7, n = (ix >> 3) & 15, kc = (ix >> 7) & 3, ks = ix >> 9;
    int k = ks * 32 + kc * 8 + e;
    float v = (n < 8) ? W3[k * 1032 + n * 65 + 64] : 0.0f;
    W3X[ix] = f2bf(v);
  } else if (blk < 1048) {
    int k = blk - 1040, c = tid;
    float s = 0.0f;
    for (int m = 0; m < 256; m++) s += W1[k * 256 + m] * W2[m * 256 + c];
    W12P[c * 8 + k] = f2bf(s);
  } else {
    int c = tid;
    float s = b2[c];
    for (int m = 0; m < 256; m++) s += b1[m] * W2[m * 256 + c];
    b12[c] = s;
  }
}

// ---------------------------------------------------------------------------
// BARRIER-FREE fused kernel: 1 wave per block, 32 rows per wave, 2048 blocks.
// R11: TRANSPOSED GEMM3 (W3 frags = A operand, a3 h-frags = B operand).
// Output lands postprocess-native: lane (kc,l15), pass mi handles row mi*16+l15
// and owns V[16kc,+16) / W[16kc,+16) IN REGISTERS -> no params LDS at all
// (epilogue's 64 ds_writes + P reads deleted). Postprocess = 2 passes x 16-step
// scan (2x ILP vs one 32-chain). Biases from padded b3 copy in LDS (aliases H).
// lj accumulates in regs, shfl-reduced at end.
// LDS 18944 B -> 8 blocks/CU; (64,2) -> 256-reg budget (~235 live, no spill).
// LDS map: H [0,16384) bf16 [32][256] swizzled (dead after a3 hoist;
//   b3V [0,2176) 8 rows x 68f / b3W [2176,4224) 8 x 64f alias it);
//   XC [16384,16896) ; xt [16896,17920) ; v64 [17920,18944).
// ---------------------------------------------------------------------------
__global__ __launch_bounds__(64, 2) void fused_pwquad(
    const float* __restrict__ x, const float* __restrict__ b3,
    const unsigned short* __restrict__ W12P, const float* __restrict__ b12,
    const unsigned short* __restrict__ W3Q, const unsigned short* __restrict__ W3X,
    float* __restrict__ out)
{
  __shared__ char smem[18944];
  char*  H     = smem;
  float* b3V   = (float*)smem;           // aliases H (written after H dead)
  float* b3W   = (float*)(smem + 2176);
  char*  XC    = smem + 16384;
  float* xt_s  = (float*)(smem + 16896);
  float* v64_s = (float*)(smem + 17920);

  const int lane = threadIdx.x & 63;
  const int kc   = lane >> 4;
  const int l15  = lane & 15;
  const int r0   = blockIdx.x * 32;

  // ---- phase 0: load 32 rows of x; emit copied (even) z cols; stash xc/xt ----
  {
    const float4* xin = (const float4*)(x + (size_t)r0 * 16);
    #pragma unroll
    for (int i = 0; i < 2; i++) {
      int f = i * 64 + lane;
      float4 v = xin[f];
      int row = f >> 2, q = f & 3;
      out[(size_t)(r0 + row) * 16 + 4 * q + 0] = fminf(v.x, 1.0f);
      out[(size_t)(r0 + row) * 16 + 4 * q + 2] = fminf(v.z, 1.0f);
      unsigned pk = (unsigned)f2bf(v.x) | ((unsigned)f2bf(v.z) << 16);
      *(unsigned*)(XC + row * 16 + q * 4) = pk;
      float2 t2; t2.x = v.y; t2.y = v.w;
      *(float2*)(xt_s + row * 8 + 2 * q) = t2;
    }
  }

  // ---- GEMM-h: h = relu(xc @ W12 + b12), 32 rows x 256 cols, K=8 ----
  {
    s16x8 ah[2] = {};
    if (kc == 0) {
      #pragma unroll
      for (int mi = 0; mi < 2; mi++) ah[mi] = *(const s16x8*)(XC + (mi * 16 + l15) * 16);
    }
    #pragma unroll
    for (int c = 0; c < 4; c++) {
      s16x8 bh[4];
      #pragma unroll
      for (int nt = 0; nt < 4; nt++)
        bh[nt] = *(const s16x8*)(W12P + (size_t)(c * 64 + nt * 16 + l15) * 8);
      fx4 acc[2][4];
      #pragma unroll
      for (int mi = 0; mi < 2; mi++)
        #pragma unroll
        for (int nt = 0; nt < 4; nt++) acc[mi][nt] = (fx4){0.f, 0.f, 0.f, 0.f};
      #pragma unroll
      for (int mi = 0; mi < 2; mi++)
        #pragma unroll
        for (int nt = 0; nt < 4; nt++) acc[mi][nt] = MFMA(ah[mi], bh[nt], acc[mi][nt]);
      #pragma unroll
      for (int nt = 0; nt < 4; nt++) {
        int col = c * 64 + nt * 16 + l15;
        float bias = b12[col];
        #pragma unroll
        for (int mi = 0; mi < 2; mi++) {
          #pragma unroll
          for (int rg = 0; rg < 4; rg++) {
            int row = mi * 16 + kc * 4 + rg;
            float v = fmaxf(acc[mi][nt][rg] + bias, 0.0f);
            int byte = (row << 9) + (col << 1);
            byte ^= ((row & 7) << 4);
            *(unsigned short*)(H + byte) = f2bf(v);
          }
        }
      }
    }
  }

  // ---- hoist h B-frags (own 32 rows, all K); V65 GEMM ----
  s16x8 a3[2][8];
  #pragma unroll
  for (int mi = 0; mi < 2; mi++) {
    #pragma unroll
    for (int ks = 0; ks < 8; ks++) {
      int row = mi * 16 + l15;
      int byte = (row << 9) + ks * 64 + (kc << 4);
      byte ^= ((row & 7) << 4);
      a3[mi][ks] = *(const s16x8*)(H + byte);
    }
  }
  {
    fx4 ax0 = (fx4){0.f, 0.f, 0.f, 0.f}, ax1 = ax0;
    #pragma unroll
    for (int ks = 0; ks < 8; ks++) {
      s16x8 bx = *(const s16x8*)(W3X + ((size_t)(ks * 4 + kc) * 16 + l15) * 8);
      ax0 = MFMA(a3[0][ks], bx, ax0);
      ax1 = MFMA(a3[1][ks], bx, ax1);
    }
    if (l15 < 8) {
      float bias = b3[l15 * 65 + 64];
      #pragma unroll
      for (int rg = 0; rg < 4; rg++) {
        v64_s[(kc * 4 + rg) * 8 + l15]      = ax0[rg] + bias;
        v64_s[(16 + kc * 4 + rg) * 8 + l15] = ax1[rg] + bias;
      }
    }
  }

  // ---- H dead: copy b3 biases into padded LDS tables (aliases H) ----
  #pragma unroll
  for (int t = 0; t < 8; t++) {
    b3V[t * 68 + lane] = b3[t * 65 + lane];          // V biases 0..63
    b3W[t * 64 + lane] = b3[520 + t * 64 + lane];    // W biases 0..63
  }

  // per-lane W3Q base; frag (t,ks,nti) at + t*65536 + ks*8192 + nti*1024
  const char* wp = (const char*)W3Q + (size_t)lane * 16;

  s16x8 F0[8], F1[8];
  #pragma unroll
  for (int nti = 0; nti < 8; nti++) F0[nti] = *(const s16x8*)(wp + nti * 1024);

  float ljacc[2] = {0.0f, 0.0f};

  #pragma unroll 1
  for (int t = 0; t < 8; t++) {
    const char* wk = wp + (size_t)t * 65536;

    fx4 accT[8][2];
    #pragma unroll
    for (int nti = 0; nti < 8; nti++) {
      accT[nti][0] = (fx4){0.f, 0.f, 0.f, 0.f};
      accT[nti][1] = (fx4){0.f, 0.f, 0.f, 0.f};
    }

    // WAR-bounded 2-deep W3 stream: reload of a frag-set sits AFTER its MFMAs.
    // At kp==3 the F0 reload (e0+16384) is exactly (t+1, ks=0).
    #pragma unroll
    for (int kp = 0; kp < 4; kp++) {
      const char* e0 = wk + kp * 16384;
      #pragma unroll
      for (int nti = 0; nti < 8; nti++) F1[nti] = *(const s16x8*)(e0 + 8192 + nti * 1024);
      __builtin_amdgcn_s_setprio(1);
      #pragma unroll
      for (int nti = 0; nti < 8; nti++) {
        accT[nti][0] = MFMA(F0[nti], a3[0][2 * kp], accT[nti][0]);
        accT[nti][1] = MFMA(F0[nti], a3[1][2 * kp], accT[nti][1]);
      }
      __builtin_amdgcn_s_setprio(0);
      if (kp < 3 || t < 7) {
        #pragma unroll
        for (int nti = 0; nti < 8; nti++) F0[nti] = *(const s16x8*)(e0 + 16384 + nti * 1024);
      }
      __builtin_amdgcn_s_setprio(1);
      #pragma unroll
      for (int nti = 0; nti < 8; nti++) {
        accT[nti][0] = MFMA(F1[nti], a3[0][2 * kp + 1], accT[nti][0]);
        accT[nti][1] = MFMA(F1[nti], a3[1][2 * kp + 1], accT[nti][1]);
      }
      __builtin_amdgcn_s_setprio(0);
    }

    // ---- postprocess: params are IN REGISTERS. Lane (kc,l15), pass mi:
    //      row = mi*16+l15; owns V[16kc,+16) = accT[0..3][mi], W[16kc,+16) = accT[4..7][mi]
    fx4 vb[4], wb[4];
    {
      const float* bV = b3V + t * 68 + 16 * kc;   // 16B-aligned (272t + 64kc)
      const float* bW = b3W + t * 64 + 16 * kc;
      #pragma unroll
      for (int i = 0; i < 4; i++) { vb[i] = *(const fx4*)(bV + 4 * i); wb[i] = *(const fx4*)(bW + 4 * i); }
    }

    #pragma unroll
    for (int mi = 0; mi < 2; mi++) {
      int row = mi * 16 + l15;
      float xtv   = xt_s[row * 8 + t];
      float vlast = v64_s[row * 8 + t];

      // W logits + bias; wmax over row (4 lanes: xor 16,32)
      float wj[16];
      float wmax = -3.0e38f;
      #pragma unroll
      for (int i = 0; i < 4; i++)
        #pragma unroll
        for (int j = 0; j < 4; j++) {
          wj[4 * i + j] = accT[4 + i][mi][j] + wb[i][j];
          wmax = fmaxf(wmax, wj[4 * i + j]);
        }
      wmax = fmaxf(wmax, __shfl_xor(wmax, 16, 64));
      wmax = fmaxf(wmax, __shfl_xor(wmax, 32, 64));

      float esum = 0.0f;
      #pragma unroll
      for (int j = 0; j < 16; j++) { wj[j] = __expf(wj[j] - wmax); esum += wj[j]; }

      // ordered 4-lane prefix (groups strided by 16)
      float g0 = __shfl(esum, l15, 64);
      float g1 = __shfl(esum, l15 + 16, 64);
      float g2 = __shfl(esum, l15 + 32, 64);
      float g3 = __shfl(esum, l15 + 48, 64);
      float S = (g0 + g1) + (g2 + g3);
      float ebase = 0.0f;
      if (kc > 0) ebase += g0;
      if (kc > 1) ebase += g1;
      if (kc > 2) ebase += g2;
      float xs = xtv * S;

      // V boundary: V[16(kc+1)] from next lane's V[0] (kc==3 -> v64)
      float v0my = accT[0][mi][0] + vb[0][0];
      float vnext = __shfl(v0my, l15 + (((kc + 1) & 3) << 4), 64);
      if (kc == 3) vnext = vlast;

      // fused 16-step scan (register-sourced V/W)
      float run = ebase;
      float evc = __expf(v0my);
      float evprev = evc, tlast = 0.0f;
      float dl = 0.0f, cpart = 0.0f;
      float wpadc = 0.0f, wbbc = 1.0f, evb = evc, evb1 = evc;
      int cnt = 0;
      #pragma unroll
      for (int j = 0; j < 16; j++) {
        float vr = (j < 15) ? (accT[(j + 1) >> 2][mi][(j + 1) & 3] + vb[(j + 1) >> 2][(j + 1) & 3])
                            : vnext;
        float evn = __expf(vr);
        float wbj = wj[j];
        float nw = run + wbj;
        float term = (evc + evn) * wbj;
        bool le = (nw <= xs);
        bool hit = (!le) && (run <= xs);
        dl += term;
        if (le) { cpart += term; cnt++; }
        if (hit) { wpadc = run; wbbc = wbj; evb = evc; evb1 = evn; }
        tlast = term;
        evprev = evc;
        run = nw; evc = evn;
      }
      int bloc = (cnt < 16) ? (kc * 16 + cnt) : 64;
      int bmin = min(bloc, __shfl_xor(bloc, 16, 64));
      bmin = min(bmin, __shfl_xor(bmin, 32, 64));

      float d0 = __shfl(dl, l15, 64);
      float d1 = __shfl(dl, l15 + 16, 64);
      float d2 = __shfl(dl, l15 + 32, 64);
      float d3 = __shfl(dl, l15 + 48, 64);
      float dltot = (d0 + d1) + (d2 + d3);
      float cbase2 = 0.0f;
      if (kc > 0) cbase2 += d0;
      if (kc > 1) cbase2 += d1;
      if (kc > 2) cbase2 += d2;

      if (bmin == 64) {  // no strict crossing: continuous fallback b=63 (kc==3 owns)
        wbbc = wj[15];
        wpadc = run - wbbc;
        evb = evprev; evb1 = evc;
        cpart = dl - tlast;
        bmin = 63;
      }

      if (kc == (bmin >> 4)) {
        float alpha = (xs - wpadc) / wbbc;          // softmax scale cancels
        float Cnum = (alpha * (evb + 0.5f * alpha * (evb1 - evb))) * wbbc
                   + 0.5f * (cbase2 + cpart);
        out[(size_t)(r0 + row) * 16 + 2 * t + 1] = fminf(Cnum / (0.5f * dltot), 1.0f);
        float qn = evb + alpha * (evb1 - evb);
        float denomt = 0.5f * dltot / S;            // true denominator
        ljacc[mi] += __logf(qn) - __logf(denomt);
      }
    }
  }

  // ---- log_J: sum ljacc across the row's 4 lanes; lane kc==0 writes ----
  #pragma unroll
  for (int mi = 0; mi < 2; mi++) {
    float v = ljacc[mi];
    v += __shfl_xor(v, 16, 64);
    v += __shfl_xor(v, 32, 64);
    if (kc == 0) out[(size_t)NROWS * 16 + r0 + mi * 16 + l15] = v;
  }
}

extern "C" void kernel_launch(void* const* d_in, const int* in_sizes, int n_in,
                              void* d_out, int out_size, void* d_ws, size_t ws_size,
                              hipStream_t stream) {
  const float* x  = (const float*)d_in[0];
  const float* W1 = (const float*)d_in[1];
  const float* b1 = (const float*)d_in[2];
  const float* W2 = (const float*)d_in[3];
  const float* b2 = (const float*)d_in[4];
  const float* W3 = (const float*)d_in[5];
  const float* b3 = (const float*)d_in[6];

  unsigned short* W12P = (unsigned short*)d_ws;                      // 4096 B
  float*          b12  = (float*)((char*)d_ws + 4096);               // 1024 B
  unsigned short* W3Q  = (unsigned short*)((char*)d_ws + 5120);      // 524288 B
  unsigned short* W3X  = (unsigned short*)((char*)d_ws + 529408);    // 8192 B

  pack_weights<<<dim3(1049), dim3(256), 0, stream>>>(W1, b1, W2, b2, W3, W12P, b12, W3Q, W3X);
  fused_pwquad<<<dim3(NROWS / 32), dim3(64), 0, stream>>>(
      x, b3, W12P, b12, W3Q, W3X, (float*)d_out);
}